// Round 1
// baseline (4850.997 us; speedup 1.0000x reference)
//
#include <hip/hip_runtime.h>
#include <math.h>

#define NVOX 8192
#define CCH 768
#define NH 12
#define DH 64
#define NBLK 12
#define NG 32
#define OUT_CH 448
#define OUT_PAD 512
#define CAP 48
#define APITCH 72  // LDS row pitch (bf16) for Q/K/P/Vt: 144 B rows, 16B-aligned

typedef __attribute__((ext_vector_type(8))) short v8s;
typedef __attribute__((ext_vector_type(4))) float v4f;

__device__ __forceinline__ unsigned short f2bf(float f) {
  unsigned u = __builtin_bit_cast(unsigned, f);
  u += 0x7fffu + ((u >> 16) & 1u);  // RNE
  return (unsigned short)(u >> 16);
}
__device__ __forceinline__ float bf2f(unsigned short b) {
  return __builtin_bit_cast(float, (unsigned)b << 16);
}

__device__ __forceinline__ void async16(const void* g, void* l) {
  __builtin_amdgcn_global_load_lds(
      (const __attribute__((address_space(1))) unsigned int*)g,
      (__attribute__((address_space(3))) unsigned int*)l, 16, 0, 0);
}

// ---------------------------------------------------------------------------
// prep: cap = max(vslot)+1 for both window configs
// ---------------------------------------------------------------------------
__global__ __launch_bounds__(256) void cap_kernel(const int* __restrict__ a,
                                                  const int* __restrict__ b,
                                                  int n, int* __restrict__ caps) {
  __shared__ int s0[256], s1[256];
  int m0 = 0, m1 = 0;
  for (int i = threadIdx.x; i < n; i += 256) {
    m0 = max(m0, a[i]);
    m1 = max(m1, b[i]);
  }
  s0[threadIdx.x] = m0;
  s1[threadIdx.x] = m1;
  __syncthreads();
  for (int st = 128; st > 0; st >>= 1) {
    if (threadIdx.x < st) {
      s0[threadIdx.x] = max(s0[threadIdx.x], s0[threadIdx.x + st]);
      s1[threadIdx.x] = max(s1[threadIdx.x], s1[threadIdx.x + st]);
    }
    __syncthreads();
  }
  if (threadIdx.x == 0) {
    caps[0] = s0[0] + 1;
    caps[1] = s1[0] + 1;
  }
}

// ---------------------------------------------------------------------------
// embed: h = feats @ in_w + in_b + pos_embed(coords)   (fp32 residual stream)
// ---------------------------------------------------------------------------
__global__ __launch_bounds__(256) void embed_kernel(const float* __restrict__ feats,
                                                    const int* __restrict__ coords,
                                                    const float* __restrict__ in_w,
                                                    const float* __restrict__ in_b,
                                                    float* __restrict__ h) {
  int id = blockIdx.x * 256 + threadIdx.x;
  if (id >= NVOX * CCH) return;
  int n = id / CCH, c = id - n * CCH;
  float acc = in_b[c];
#pragma unroll
  for (int k = 0; k < 8; ++k) acc += feats[n * 8 + k] * in_w[k * CCH + c];
  int axis = c / 256;
  int r = c - axis * 256;
  int f = r & 127;
  float freq = __expf(-(float)f * (9.210340371976184f / 128.0f));  // ln(10000)
  float phase = (float)coords[n * 3 + axis] * freq;
  acc += (r < 128) ? __sinf(phase) : __cosf(phase);
  h[id] = acc;
}

// ---------------------------------------------------------------------------
// layernorm (no affine) -> bf16 output (A-operand of following GEMM)
// ---------------------------------------------------------------------------
__global__ __launch_bounds__(256) void ln_kernel(const float* __restrict__ x,
                                                 unsigned short* __restrict__ y,
                                                 float eps) {
  int row = blockIdx.x;
  const float* xr = x + (size_t)row * CCH;
  float v[3];
  float s = 0.f, s2 = 0.f;
#pragma unroll
  for (int j = 0; j < 3; ++j) {
    v[j] = xr[threadIdx.x + j * 256];
    s += v[j];
    s2 += v[j] * v[j];
  }
#pragma unroll
  for (int off = 32; off >= 1; off >>= 1) {
    s += __shfl_xor(s, off, 64);
    s2 += __shfl_xor(s2, off, 64);
  }
  __shared__ float ss[4], ss2[4];
  int wave = threadIdx.x >> 6, lane = threadIdx.x & 63;
  if (lane == 0) { ss[wave] = s; ss2[wave] = s2; }
  __syncthreads();
  s = ss[0] + ss[1] + ss[2] + ss[3];
  s2 = ss2[0] + ss2[1] + ss2[2] + ss2[3];
  float mu = s * (1.0f / CCH);
  float var = s2 * (1.0f / CCH) - mu * mu;
  float rr = rsqrtf(var + eps);
  unsigned short* yr = y + (size_t)row * CCH;
#pragma unroll
  for (int j = 0; j < 3; ++j) yr[threadIdx.x + j * 256] = f2bf((v[j] - mu) * rr);
}

// ---------------------------------------------------------------------------
// weight convert: W fp32 [K][Nsrc] -> Wt bf16 [N][K] (transposed; n>=Nsrc -> 0)
// ---------------------------------------------------------------------------
__device__ __forceinline__ void wconv_tile(const float* __restrict__ W,
                                           unsigned short* __restrict__ Wt,
                                           int K, int Nsrc, int nt, int kt,
                                           float (*t)[65]) {
  int n0 = nt * 64, k0 = kt * 64;
  for (int e = threadIdx.x; e < 4096; e += 256) {
    int r = e >> 6, c = e & 63;
    int n = n0 + c;
    t[r][c] = (n < Nsrc) ? W[(size_t)(k0 + r) * Nsrc + n] : 0.f;
  }
  __syncthreads();
  for (int e = threadIdx.x; e < 4096; e += 256) {
    int rn = e >> 6, ck = e & 63;
    Wt[(size_t)(n0 + rn) * K + k0 + ck] = f2bf(t[ck][rn]);
  }
}

__global__ __launch_bounds__(256) void wconvert(const float* __restrict__ W,
                                                unsigned short* __restrict__ Wt,
                                                int K, int Nsrc) {
  __shared__ float t[64][65];
  wconv_tile(W, Wt, K, Nsrc, blockIdx.x, blockIdx.y, t);
}

// fused: all 4 weights of one block in one launch (1728 tiles)
__global__ __launch_bounds__(256) void wconvert4(const float* __restrict__ W0,
                                                 const float* __restrict__ W1,
                                                 const float* __restrict__ W2,
                                                 const float* __restrict__ W3,
                                                 unsigned short* __restrict__ D0,
                                                 unsigned short* __restrict__ D1,
                                                 unsigned short* __restrict__ D2,
                                                 unsigned short* __restrict__ D3) {
  __shared__ float t[64][65];
  int b = blockIdx.x;
  if (b < 432) {
    wconv_tile(W0, D0, 768, 2304, b / 12, b % 12, t);        // qkv 768x2304
  } else if (b < 576) {
    b -= 432;
    wconv_tile(W1, D1, 768, 768, b / 12, b % 12, t);         // proj 768x768
  } else if (b < 1152) {
    b -= 576;
    wconv_tile(W2, D2, 768, 3072, b / 12, b % 12, t);        // mlp1 768x3072
  } else {
    b -= 1152;
    wconv_tile(W3, D3, 3072, 768, b / 48, b % 48, t);        // mlp2 3072x768
  }
}

// ---------------------------------------------------------------------------
// bf16 MFMA GEMM (m97 structure): out[M,Nn] = act(A[M,K] @ Bt[Nn,K]^T + bias)
// SPLITK > 1: blockIdx.z owns K-range [z*K/SPLITK, (z+1)*K/SPLITK);
//             requires RES=1 path (partials atomicAdd into fp32 residual).
// XCD-aware bijective tile swizzle (m204) for per-XCD L2 panel reuse.
// ---------------------------------------------------------------------------
__device__ __forceinline__ float gelu_exact(float x) {
  return 0.5f * x * (1.0f + erff(x * 0.70710678118654752f));
}

template <int ACT, int RES, int OUTBF, int SPLITK>
__global__ __launch_bounds__(256) void gemm_mfma(const unsigned short* __restrict__ A,
                                                 const unsigned short* __restrict__ Bt,
                                                 const float* __restrict__ bias, int Nbias,
                                                 float* __restrict__ outf,
                                                 unsigned short* __restrict__ outb,
                                                 int Nn, int K) {
  __shared__ __align__(16) unsigned short As[128 * 32];
  __shared__ __align__(16) unsigned short Bs[128 * 32];
  const int tid = threadIdx.x;
  const int lane = tid & 63, w = tid >> 6;

  // m204 bijective XCD swizzle on the (x,y) tile grid
  int bx = blockIdx.x, by = blockIdx.y;
  {
    const int gx = gridDim.x, gy = gridDim.y;
    const int nwg = gx * gy;
    const int id = by * gx + bx;
    const int q = nwg >> 3, r = nwg & 7;
    const int xc = id & 7, off = id >> 3;
    const int nid = (xc < r ? xc * (q + 1) : r * (q + 1) + (xc - r) * q) + off;
    bx = nid % gx;
    by = nid / gx;
  }
  const int row0 = by * 128, col0 = bx * 128;
  const int wm = (w >> 1) * 64, wn = (w & 1) * 64;
  const int fm = lane & 15, fq = lane >> 4;

  const int kz = (SPLITK > 1) ? blockIdx.z : 0;
  const int Keff = K / SPLITK;
  const int kbase = kz * Keff;

  const int c0 = w * 64 + lane;
  const int c1 = c0 + 256;
  const unsigned short* gA0 = A + (size_t)(row0 + (c0 >> 2)) * K + (c0 & 3) * 8;
  const unsigned short* gA1 = A + (size_t)(row0 + (c1 >> 2)) * K + (c1 & 3) * 8;
  const unsigned short* gB0 = Bt + (size_t)(col0 + (c0 >> 2)) * K + (c0 & 3) * 8;
  const unsigned short* gB1 = Bt + (size_t)(col0 + (c1 >> 2)) * K + (c1 & 3) * 8;
  unsigned short* lA0 = As + (size_t)(w * 64) * 8;
  unsigned short* lA1 = As + (size_t)(w * 64 + 256) * 8;
  unsigned short* lB0 = Bs + (size_t)(w * 64) * 8;
  unsigned short* lB1 = Bs + (size_t)(w * 64 + 256) * 8;

  v4f acc[4][4];
#pragma unroll
  for (int i = 0; i < 4; ++i)
#pragma unroll
    for (int j = 0; j < 4; ++j) acc[i][j] = (v4f){0.f, 0.f, 0.f, 0.f};

  for (int k0 = kbase; k0 < kbase + Keff; k0 += 32) {
    async16(gA0 + k0, lA0);
    async16(gA1 + k0, lA1);
    async16(gB0 + k0, lB0);
    async16(gB1 + k0, lB1);
    __syncthreads();
    v8s af[4], bf[4];
#pragma unroll
    for (int i = 0; i < 4; ++i)
      af[i] = *(const v8s*)(As + (size_t)(wm + i * 16 + fm) * 32 + fq * 8);
#pragma unroll
    for (int j = 0; j < 4; ++j)
      bf[j] = *(const v8s*)(Bs + (size_t)(wn + j * 16 + fm) * 32 + fq * 8);
#pragma unroll
    for (int i = 0; i < 4; ++i)
#pragma unroll
      for (int j = 0; j < 4; ++j)
        acc[i][j] = __builtin_amdgcn_mfma_f32_16x16x32_bf16(af[i], bf[j], acc[i][j], 0, 0, 0);
    __syncthreads();
  }

#pragma unroll
  for (int i = 0; i < 4; ++i) {
    int row = row0 + wm + i * 16 + fq * 4;
#pragma unroll
    for (int j = 0; j < 4; ++j) {
      int col = col0 + wn + j * 16 + fm;
      float b = (col < Nbias) ? bias[col] : 0.f;
      if (SPLITK > 1 && kz != 0) b = 0.f;  // bias only once across splits
#pragma unroll
      for (int r = 0; r < 4; ++r) {
        float v = acc[i][j][r] + b;
        if (ACT == 1) v = gelu_exact(v);
        size_t o = (size_t)(row + r) * Nn + col;
        if (RES) {
          if (SPLITK > 1) {
            atomicAdd(outf + o, v);
          } else {
            outf[o] += v;
          }
        } else if (OUTBF) {
          outb[o] = f2bf(v);
        } else {
          outf[o] = v;
        }
      }
    }
  }
}

// ---------------------------------------------------------------------------
// MFMA windowed attention: one wave per (window, head).
// S = Q.K^T (3x3 tiles of 16x16x32), in-register masked softmax (rden folded),
// P (bf16, aliased over Q) . V -> O (3x4 tiles), scatter bf16 store.
// ---------------------------------------------------------------------------
__global__ __launch_bounds__(64) void attn_kernel(const unsigned short* __restrict__ qkv,
                                                  const int* __restrict__ idx,
                                                  const int* __restrict__ capPtr,
                                                  int total,
                                                  unsigned short* __restrict__ attn_out) {
  __shared__ __align__(16) unsigned short QP[CAP * APITCH];  // Q, then P
  __shared__ __align__(16) unsigned short Ks[CAP * APITCH];
  __shared__ __align__(16) unsigned short Vt[64 * APITCH];   // V transposed [d][j]
  __shared__ int vox_lds[64];
  const int cap = *capPtr;
  if (cap > CAP) return;  // loud failure rather than OOB
  const int nw = total / cap;
  const int tasks = nw * NH;
  const int lane = threadIdx.x;
  const int fm = lane & 15, fq = lane >> 4;
  const v8s z8 = {0, 0, 0, 0, 0, 0, 0, 0};

  for (int task = blockIdx.x; task < tasks; task += gridDim.x) {
    const int w = task / NH, hh = task - w * NH;
    int vox_i = NVOX;
    if (lane < cap) vox_i = idx[w * cap + lane];
    vox_lds[lane] = vox_i;
    __syncthreads();

    // stage Q,K: 48 rows x 8 chunks of 8 bf16; lane covers (row, chunk)
#pragma unroll
    for (int it = 0; it < 6; ++it) {
      int id = it * 64 + lane;  // 0..383
      int j = id >> 3, c = id & 7;
      int vj = vox_lds[j];
      v8s q8 = z8, k8 = z8;
      if (vj < NVOX) {
        const unsigned short* base = qkv + (size_t)vj * (3 * CCH) + hh * DH + c * 8;
        q8 = *(const v8s*)(base);
        k8 = *(const v8s*)(base + CCH);
      }
      *(v8s*)(QP + j * APITCH + c * 8) = q8;
      *(v8s*)(Ks + j * APITCH + c * 8) = k8;
    }
    // stage V transposed: lane = d, column j
#pragma unroll 4
    for (int j = 0; j < CAP; ++j) {
      int vj = vox_lds[j];
      unsigned short vv = 0;
      if (vj < NVOX) vv = qkv[(size_t)vj * (3 * CCH) + 2 * CCH + hh * DH + lane];
      Vt[lane * APITCH + j] = vv;
    }
#pragma unroll
    for (int j = CAP; j < 64; ++j) Vt[lane * APITCH + j] = 0;  // k-padding
    __syncthreads();

    // S = Q . K^T  (rows i, cols j)
    v4f s_acc[3][3];
#pragma unroll
    for (int mi = 0; mi < 3; ++mi)
#pragma unroll
      for (int jt = 0; jt < 3; ++jt) s_acc[mi][jt] = (v4f){0.f, 0.f, 0.f, 0.f};
#pragma unroll
    for (int ks = 0; ks < 2; ++ks) {
      v8s qf[3], kf[3];
#pragma unroll
      for (int mi = 0; mi < 3; ++mi)
        qf[mi] = *(const v8s*)(QP + (mi * 16 + fm) * APITCH + ks * 32 + fq * 8);
#pragma unroll
      for (int jt = 0; jt < 3; ++jt)
        kf[jt] = *(const v8s*)(Ks + (jt * 16 + fm) * APITCH + ks * 32 + fq * 8);
#pragma unroll
      for (int mi = 0; mi < 3; ++mi)
#pragma unroll
        for (int jt = 0; jt < 3; ++jt)
          s_acc[mi][jt] = __builtin_amdgcn_mfma_f32_16x16x32_bf16(qf[mi], kf[jt], s_acc[mi][jt], 0, 0, 0);
    }
    __syncthreads();  // Q fragment reads complete before P overwrites QP

    // masked softmax in C-layout registers; scale 1/8 folded into exp,
    // 1/den folded into P. Scores are O(1) here -> exp without max-subtract.
    bool va0 = (fm < cap) && (vox_lds[fm] < NVOX);
    bool va1 = (16 + fm < cap) && (vox_lds[16 + fm] < NVOX);
    bool va2 = (32 + fm < cap) && (vox_lds[32 + fm] < NVOX);
#pragma unroll
    for (int mi = 0; mi < 3; ++mi) {
#pragma unroll
      for (int r = 0; r < 4; ++r) {
        float e0 = va0 ? __expf(s_acc[mi][0][r] * 0.125f) : 0.f;
        float e1 = va1 ? __expf(s_acc[mi][1][r] * 0.125f) : 0.f;
        float e2 = va2 ? __expf(s_acc[mi][2][r] * 0.125f) : 0.f;
        float den = e0 + e1 + e2;
        den += __shfl_xor(den, 1, 64);
        den += __shfl_xor(den, 2, 64);
        den += __shfl_xor(den, 4, 64);
        den += __shfl_xor(den, 8, 64);
        float rden = (den > 0.f) ? 1.0f / den : 0.f;
        int row = mi * 16 + fq * 4 + r;
        QP[row * APITCH + fm] = f2bf(e0 * rden);
        QP[row * APITCH + 16 + fm] = f2bf(e1 * rden);
        QP[row * APITCH + 32 + fm] = f2bf(e2 * rden);
      }
    }
    if (lane < CAP) {  // zero P cols 48..64 (k padding for PV)
      *(v8s*)(QP + lane * APITCH + 48) = z8;
      *(v8s*)(QP + lane * APITCH + 56) = z8;
    }
    __syncthreads();

    // O = P . V   (rows i, cols d)
    v4f o_acc[3][4];
#pragma unroll
    for (int mi = 0; mi < 3; ++mi)
#pragma unroll
      for (int nt = 0; nt < 4; ++nt) o_acc[mi][nt] = (v4f){0.f, 0.f, 0.f, 0.f};
#pragma unroll
    for (int ks = 0; ks < 2; ++ks) {
      v8s pf[3], vf[4];
#pragma unroll
      for (int mi = 0; mi < 3; ++mi)
        pf[mi] = *(const v8s*)(QP + (mi * 16 + fm) * APITCH + ks * 32 + fq * 8);
#pragma unroll
      for (int nt = 0; nt < 4; ++nt)
        vf[nt] = *(const v8s*)(Vt + (nt * 16 + fm) * APITCH + ks * 32 + fq * 8);
#pragma unroll
      for (int mi = 0; mi < 3; ++mi)
#pragma unroll
        for (int nt = 0; nt < 4; ++nt)
          o_acc[mi][nt] = __builtin_amdgcn_mfma_f32_16x16x32_bf16(pf[mi], vf[nt], o_acc[mi][nt], 0, 0, 0);
    }

    // scatter store O rows
#pragma unroll
    for (int mi = 0; mi < 3; ++mi) {
#pragma unroll
      for (int r = 0; r < 4; ++r) {
        int i = mi * 16 + fq * 4 + r;
        int vox = vox_lds[i];
        if (i < cap && vox < NVOX) {
          unsigned short* ob = attn_out + (size_t)vox * CCH + hh * DH + fm;
#pragma unroll
          for (int nt = 0; nt < 4; ++nt) ob[nt * 16] = f2bf(o_acc[mi][nt][r]);
        }
      }
    }
    __syncthreads();  // P/Vt reads done before next task's staging
  }
}

// ---------------------------------------------------------------------------
// gaussian decode: reads padded [N][512] fp32, writes d_out [N][448]
// ---------------------------------------------------------------------------
__global__ __launch_bounds__(256) void decode_kernel(const float* __restrict__ outpad,
                                                     const int* __restrict__ coords,
                                                     const float* __restrict__ perturb,
                                                     float* __restrict__ out) {
  __shared__ float row[OUT_CH];
  const int n = blockIdx.x;
  const float* src = outpad + (size_t)n * OUT_PAD;
  for (int e = threadIdx.x; e < OUT_CH; e += 256) row[e] = src[e];
  __syncthreads();
  float* o = out + (size_t)n * OUT_CH;
  for (int e = threadIdx.x; e < OUT_CH; e += 256) {
    int g = e / 14, j = e - g * 14;
    float v;
    if (j < 3) {
      float xyz = ((float)coords[n * 3 + j] + 0.5f) * (1.0f / 64.0f);
      v = xyz + tanhf(row[g * 3 + j] + perturb[g * 3 + j]) * (0.75f / 64.0f);
    } else if (j < 6) {
      v = row[96 + g * 3 + (j - 3)];
    } else if (j < 9) {
      v = row[192 + g * 3 + (j - 6)];
    } else if (j < 13) {
      v = row[288 + g * 4 + (j - 9)] * 0.1f;
    } else {
      v = row[416 + g];
    }
    o[e] = v;
  }
}

// ---------------------------------------------------------------------------
extern "C" void kernel_launch(void* const* d_in, const int* in_sizes, int n_in,
                              void* d_out, int out_size, void* d_ws, size_t ws_size,
                              hipStream_t stream) {
  const float* feats = (const float*)d_in[0];
  const int* coords = (const int*)d_in[1];
  const float* in_w = (const float*)d_in[2];
  const float* in_b = (const float*)d_in[3];
  const float* qkv_w = (const float*)d_in[4];
  const float* qkv_b = (const float*)d_in[5];
  const float* proj_w = (const float*)d_in[6];
  const float* proj_b = (const float*)d_in[7];
  const float* mlp_w1 = (const float*)d_in[8];
  const float* mlp_b1 = (const float*)d_in[9];
  const float* mlp_w2 = (const float*)d_in[10];
  const float* mlp_b2 = (const float*)d_in[11];
  const float* out_w = (const float*)d_in[12];
  const float* out_b = (const float*)d_in[13];
  const float* perturb = (const float*)d_in[14];
  const int* idx0 = (const int*)d_in[15];
  const int* vslot0 = (const int*)d_in[18];
  const int* idx1 = (const int*)d_in[19];
  const int* vslot1 = (const int*)d_in[22];
  const int total0 = in_sizes[15];
  const int total1 = in_sizes[19];

  char* p = (char*)d_ws;
  int* caps = (int*)p;                                                    // 256 B
  float* h = (float*)(p + 256);                                           // 25165824
  unsigned short* abuf = (unsigned short*)(p + 256 + 25165824);           // 12582912
  unsigned short* big = (unsigned short*)(p + 256 + 37748736);            // 50331648
  unsigned short* wst = (unsigned short*)(p + 256 + 88080384);            // 14155776
  float* outpad = (float*)(p + 256 + 102236160);                          // 16777216
  const size_t OQ = 0;
  const size_t OP = (size_t)768 * 2304;
  const size_t OM1 = OP + (size_t)768 * 768;
  const size_t OM2 = OM1 + (size_t)768 * 3072;

  cap_kernel<<<1, 256, 0, stream>>>(vslot0, vslot1, NVOX, caps);
  embed_kernel<<<(NVOX * CCH + 255) / 256, 256, 0, stream>>>(feats, coords, in_w, in_b, h);

  for (int i = 0; i < NBLK; ++i) {
    const int* idx = (i & 1) ? idx1 : idx0;
    const int* capP = (i & 1) ? caps + 1 : caps;
    const int total = (i & 1) ? total1 : total0;

    wconvert4<<<1728, 256, 0, stream>>>(
        qkv_w + (size_t)i * 768 * 2304, proj_w + (size_t)i * 768 * 768,
        mlp_w1 + (size_t)i * 768 * 3072, mlp_w2 + (size_t)i * 3072 * 768,
        wst + OQ, wst + OP, wst + OM1, wst + OM2);

    ln_kernel<<<NVOX, 256, 0, stream>>>(h, abuf, 1e-6f);
    gemm_mfma<0, 0, 1, 1><<<dim3(18, 64), 256, 0, stream>>>(
        abuf, wst + OQ, qkv_b + (size_t)i * 2304, 2304, nullptr, big, 2304, 768);
    attn_kernel<<<4096, 64, 0, stream>>>(big, idx, capP, total, abuf);
    gemm_mfma<0, 1, 0, 2><<<dim3(6, 64, 2), 256, 0, stream>>>(
        abuf, wst + OP, proj_b + (size_t)i * 768, 768, h, nullptr, 768, 768);
    ln_kernel<<<NVOX, 256, 0, stream>>>(h, abuf, 1e-6f);
    gemm_mfma<1, 0, 1, 1><<<dim3(24, 64), 256, 0, stream>>>(
        abuf, wst + OM1, mlp_b1 + (size_t)i * 3072, 3072, nullptr, big, 3072, 768);
    gemm_mfma<0, 1, 0, 4><<<dim3(6, 64, 4), 256, 0, stream>>>(
        big, wst + OM2, mlp_b2 + (size_t)i * 768, 768, h, nullptr, 768, 3072);
  }

  ln_kernel<<<NVOX, 256, 0, stream>>>(h, abuf, 1e-5f);
  wconvert<<<dim3(8, 12), 256, 0, stream>>>(out_w, wst + OQ, 768, OUT_CH);
  gemm_mfma<0, 0, 0, 1><<<dim3(4, 64), 256, 0, stream>>>(
      abuf, wst + OQ, out_b, OUT_CH, outpad, nullptr, OUT_PAD, 768);
  decode_kernel<<<NVOX, 256, 0, stream>>>(outpad, coords, perturb, (float*)d_out);
}

// Round 2
// 4400.345 us; speedup vs baseline: 1.1024x; 1.1024x over previous
//
#include <hip/hip_runtime.h>
#include <math.h>

#define NVOX 8192
#define CCH 768
#define NH 12
#define DH 64
#define NBLK 12
#define NG 32
#define OUT_CH 448
#define OUT_PAD 512
#define CAP 48
#define APITCH 72  // LDS row pitch (bf16) for Q/K/P/Vt: 144 B rows, 16B-aligned

typedef __attribute__((ext_vector_type(8))) short v8s;
typedef __attribute__((ext_vector_type(4))) float v4f;

__device__ __forceinline__ unsigned short f2bf(float f) {
  unsigned u = __builtin_bit_cast(unsigned, f);
  u += 0x7fffu + ((u >> 16) & 1u);  // RNE
  return (unsigned short)(u >> 16);
}
__device__ __forceinline__ float bf2f(unsigned short b) {
  return __builtin_bit_cast(float, (unsigned)b << 16);
}

__device__ __forceinline__ void async16(const void* g, void* l) {
  __builtin_amdgcn_global_load_lds(
      (const __attribute__((address_space(1))) unsigned int*)g,
      (__attribute__((address_space(3))) unsigned int*)l, 16, 0, 0);
}

// ---------------------------------------------------------------------------
// prep: cap = max(vslot)+1 for both window configs
// ---------------------------------------------------------------------------
__global__ __launch_bounds__(256) void cap_kernel(const int* __restrict__ a,
                                                  const int* __restrict__ b,
                                                  int n, int* __restrict__ caps) {
  __shared__ int s0[256], s1[256];
  int m0 = 0, m1 = 0;
  for (int i = threadIdx.x; i < n; i += 256) {
    m0 = max(m0, a[i]);
    m1 = max(m1, b[i]);
  }
  s0[threadIdx.x] = m0;
  s1[threadIdx.x] = m1;
  __syncthreads();
  for (int st = 128; st > 0; st >>= 1) {
    if (threadIdx.x < st) {
      s0[threadIdx.x] = max(s0[threadIdx.x], s0[threadIdx.x + st]);
      s1[threadIdx.x] = max(s1[threadIdx.x], s1[threadIdx.x + st]);
    }
    __syncthreads();
  }
  if (threadIdx.x == 0) {
    caps[0] = s0[0] + 1;
    caps[1] = s1[0] + 1;
  }
}

// ---------------------------------------------------------------------------
// embed: h = feats @ in_w + in_b + pos_embed(coords)   (fp32 residual stream)
// ---------------------------------------------------------------------------
__global__ __launch_bounds__(256) void embed_kernel(const float* __restrict__ feats,
                                                    const int* __restrict__ coords,
                                                    const float* __restrict__ in_w,
                                                    const float* __restrict__ in_b,
                                                    float* __restrict__ h) {
  int id = blockIdx.x * 256 + threadIdx.x;
  if (id >= NVOX * CCH) return;
  int n = id / CCH, c = id - n * CCH;
  float acc = in_b[c];
#pragma unroll
  for (int k = 0; k < 8; ++k) acc += feats[n * 8 + k] * in_w[k * CCH + c];
  int axis = c / 256;
  int r = c - axis * 256;
  int f = r & 127;
  float freq = __expf(-(float)f * (9.210340371976184f / 128.0f));  // ln(10000)
  float phase = (float)coords[n * 3 + axis] * freq;
  acc += (r < 128) ? __sinf(phase) : __cosf(phase);
  h[id] = acc;
}

// ---------------------------------------------------------------------------
// layernorm (no affine) -> bf16 output (A-operand of following GEMM)
// ---------------------------------------------------------------------------
__global__ __launch_bounds__(256) void ln_kernel(const float* __restrict__ x,
                                                 unsigned short* __restrict__ y,
                                                 float eps) {
  int row = blockIdx.x;
  const float* xr = x + (size_t)row * CCH;
  float v[3];
  float s = 0.f, s2 = 0.f;
#pragma unroll
  for (int j = 0; j < 3; ++j) {
    v[j] = xr[threadIdx.x + j * 256];
    s += v[j];
    s2 += v[j] * v[j];
  }
#pragma unroll
  for (int off = 32; off >= 1; off >>= 1) {
    s += __shfl_xor(s, off, 64);
    s2 += __shfl_xor(s2, off, 64);
  }
  __shared__ float ss[4], ss2[4];
  int wave = threadIdx.x >> 6, lane = threadIdx.x & 63;
  if (lane == 0) { ss[wave] = s; ss2[wave] = s2; }
  __syncthreads();
  s = ss[0] + ss[1] + ss[2] + ss[3];
  s2 = ss2[0] + ss2[1] + ss2[2] + ss2[3];
  float mu = s * (1.0f / CCH);
  float var = s2 * (1.0f / CCH) - mu * mu;
  float rr = rsqrtf(var + eps);
  unsigned short* yr = y + (size_t)row * CCH;
#pragma unroll
  for (int j = 0; j < 3; ++j) yr[threadIdx.x + j * 256] = f2bf((v[j] - mu) * rr);
}

// ---------------------------------------------------------------------------
// weight convert: W fp32 [K][Nsrc] -> Wt bf16 [N][K] (transposed; n>=Nsrc -> 0)
// ---------------------------------------------------------------------------
__device__ __forceinline__ void wconv_tile(const float* __restrict__ W,
                                           unsigned short* __restrict__ Wt,
                                           int K, int Nsrc, int nt, int kt,
                                           float (*t)[65]) {
  int n0 = nt * 64, k0 = kt * 64;
  for (int e = threadIdx.x; e < 4096; e += 256) {
    int r = e >> 6, c = e & 63;
    int n = n0 + c;
    t[r][c] = (n < Nsrc) ? W[(size_t)(k0 + r) * Nsrc + n] : 0.f;
  }
  __syncthreads();
  for (int e = threadIdx.x; e < 4096; e += 256) {
    int rn = e >> 6, ck = e & 63;
    Wt[(size_t)(n0 + rn) * K + k0 + ck] = f2bf(t[ck][rn]);
  }
}

__global__ __launch_bounds__(256) void wconvert(const float* __restrict__ W,
                                                unsigned short* __restrict__ Wt,
                                                int K, int Nsrc) {
  __shared__ float t[64][65];
  wconv_tile(W, Wt, K, Nsrc, blockIdx.x, blockIdx.y, t);
}

// fused: all 4 weights of one block in one launch (1728 tiles)
__global__ __launch_bounds__(256) void wconvert4(const float* __restrict__ W0,
                                                 const float* __restrict__ W1,
                                                 const float* __restrict__ W2,
                                                 const float* __restrict__ W3,
                                                 unsigned short* __restrict__ D0,
                                                 unsigned short* __restrict__ D1,
                                                 unsigned short* __restrict__ D2,
                                                 unsigned short* __restrict__ D3) {
  __shared__ float t[64][65];
  int b = blockIdx.x;
  if (b < 432) {
    wconv_tile(W0, D0, 768, 2304, b / 12, b % 12, t);        // qkv 768x2304
  } else if (b < 576) {
    b -= 432;
    wconv_tile(W1, D1, 768, 768, b / 12, b % 12, t);         // proj 768x768
  } else if (b < 1152) {
    b -= 576;
    wconv_tile(W2, D2, 768, 3072, b / 12, b % 12, t);        // mlp1 768x3072
  } else {
    b -= 1152;
    wconv_tile(W3, D3, 3072, 768, b / 48, b % 48, t);        // mlp2 3072x768
  }
}

// ---------------------------------------------------------------------------
// bf16 MFMA GEMM, double-buffered 2-phase schedule (T3 minimum recipe):
//   issue global_load_lds for tile t+1 BEFORE ds_read+MFMA of tile t;
//   single __syncthreads() (= vmcnt(0)+barrier) per K-step. Load latency
//   hides under compute even at 1-2 blocks/CU (skinny-N dispatches).
// out[M,Nn] = act(A[M,K] @ Bt[Nn,K]^T + bias); XCD-bijective tile swizzle.
// ---------------------------------------------------------------------------
__device__ __forceinline__ float gelu_exact(float x) {
  return 0.5f * x * (1.0f + erff(x * 0.70710678118654752f));
}

template <int ACT, int RES, int OUTBF>
__global__ __launch_bounds__(256) void gemm_mfma(const unsigned short* __restrict__ A,
                                                 const unsigned short* __restrict__ Bt,
                                                 const float* __restrict__ bias, int Nbias,
                                                 float* __restrict__ outf,
                                                 unsigned short* __restrict__ outb,
                                                 int Nn, int K) {
  __shared__ __align__(16) unsigned short As[2][128 * 32];
  __shared__ __align__(16) unsigned short Bs[2][128 * 32];
  const int tid = threadIdx.x;
  const int lane = tid & 63, w = tid >> 6;

  // m204 bijective XCD swizzle on the (x,y) tile grid
  int bx = blockIdx.x, by = blockIdx.y;
  {
    const int gx = gridDim.x, gy = gridDim.y;
    const int nwg = gx * gy;
    const int id = by * gx + bx;
    const int q = nwg >> 3, r = nwg & 7;
    const int xc = id & 7, off = id >> 3;
    const int nid = (xc < r ? xc * (q + 1) : r * (q + 1) + (xc - r) * q) + off;
    bx = nid % gx;
    by = nid / gx;
  }
  const int row0 = by * 128, col0 = bx * 128;
  const int wm = (w >> 1) * 64, wn = (w & 1) * 64;
  const int fm = lane & 15, fq = lane >> 4;

  const int c0 = w * 64 + lane;
  const int c1 = c0 + 256;
  const unsigned short* gA0 = A + (size_t)(row0 + (c0 >> 2)) * K + (c0 & 3) * 8;
  const unsigned short* gA1 = A + (size_t)(row0 + (c1 >> 2)) * K + (c1 & 3) * 8;
  const unsigned short* gB0 = Bt + (size_t)(col0 + (c0 >> 2)) * K + (c0 & 3) * 8;
  const unsigned short* gB1 = Bt + (size_t)(col0 + (c1 >> 2)) * K + (c1 & 3) * 8;
  const int oL0 = w * 512;         // shorts; wave's 16-row strip, chunk 0
  const int oL1 = w * 512 + 2048;  // rows 64..127 strip

  v4f acc[4][4];
#pragma unroll
  for (int i = 0; i < 4; ++i)
#pragma unroll
    for (int j = 0; j < 4; ++j) acc[i][j] = (v4f){0.f, 0.f, 0.f, 0.f};

  // prologue: stage K-tile 0 into buffer 0
  async16(gA0, As[0] + oL0);
  async16(gA1, As[0] + oL1);
  async16(gB0, Bs[0] + oL0);
  async16(gB1, Bs[0] + oL1);
  __syncthreads();

  int cur = 0;
  for (int k0 = 32; k0 < K; k0 += 32) {
    const int nxt = cur ^ 1;
    // issue next-tile loads first — they stay in flight across the compute
    async16(gA0 + k0, As[nxt] + oL0);
    async16(gA1 + k0, As[nxt] + oL1);
    async16(gB0 + k0, Bs[nxt] + oL0);
    async16(gB1 + k0, Bs[nxt] + oL1);
    // compute current tile
    v8s af[4], bfv[4];
#pragma unroll
    for (int i = 0; i < 4; ++i)
      af[i] = *(const v8s*)(As[cur] + (wm + i * 16 + fm) * 32 + fq * 8);
#pragma unroll
    for (int j = 0; j < 4; ++j)
      bfv[j] = *(const v8s*)(Bs[cur] + (wn + j * 16 + fm) * 32 + fq * 8);
#pragma unroll
    for (int i = 0; i < 4; ++i)
#pragma unroll
      for (int j = 0; j < 4; ++j)
        acc[i][j] = __builtin_amdgcn_mfma_f32_16x16x32_bf16(af[i], bfv[j], acc[i][j], 0, 0, 0);
    __syncthreads();  // drains vmcnt(0): next buffer ready; cur reads done
    cur = nxt;
  }
  {  // epilogue tile (no prefetch)
    v8s af[4], bfv[4];
#pragma unroll
    for (int i = 0; i < 4; ++i)
      af[i] = *(const v8s*)(As[cur] + (wm + i * 16 + fm) * 32 + fq * 8);
#pragma unroll
    for (int j = 0; j < 4; ++j)
      bfv[j] = *(const v8s*)(Bs[cur] + (wn + j * 16 + fm) * 32 + fq * 8);
#pragma unroll
    for (int i = 0; i < 4; ++i)
#pragma unroll
      for (int j = 0; j < 4; ++j)
        acc[i][j] = __builtin_amdgcn_mfma_f32_16x16x32_bf16(af[i], bfv[j], acc[i][j], 0, 0, 0);
  }

#pragma unroll
  for (int i = 0; i < 4; ++i) {
    int row = row0 + wm + i * 16 + fq * 4;
#pragma unroll
    for (int j = 0; j < 4; ++j) {
      int col = col0 + wn + j * 16 + fm;
      float b = (col < Nbias) ? bias[col] : 0.f;
#pragma unroll
      for (int r = 0; r < 4; ++r) {
        float v = acc[i][j][r] + b;
        if (ACT == 1) v = gelu_exact(v);
        size_t o = (size_t)(row + r) * Nn + col;
        if (RES) {
          outf[o] += v;
        } else if (OUTBF) {
          outb[o] = f2bf(v);
        } else {
          outf[o] = v;
        }
      }
    }
  }
}

// ---------------------------------------------------------------------------
// MFMA windowed attention: one wave per (window, head).
// S = Q.K^T (3x3 tiles of 16x16x32), in-register masked softmax (rden folded),
// P (bf16, aliased over Q) . V -> O (3x4 tiles), scatter bf16 store.
// ---------------------------------------------------------------------------
__global__ __launch_bounds__(64) void attn_kernel(const unsigned short* __restrict__ qkv,
                                                  const int* __restrict__ idx,
                                                  const int* __restrict__ capPtr,
                                                  int total,
                                                  unsigned short* __restrict__ attn_out) {
  __shared__ __align__(16) unsigned short QP[CAP * APITCH];  // Q, then P
  __shared__ __align__(16) unsigned short Ks[CAP * APITCH];
  __shared__ __align__(16) unsigned short Vt[64 * APITCH];   // V transposed [d][j]
  __shared__ int vox_lds[64];
  const int cap = *capPtr;
  if (cap > CAP) return;  // loud failure rather than OOB
  const int nw = total / cap;
  const int tasks = nw * NH;
  const int lane = threadIdx.x;
  const int fm = lane & 15, fq = lane >> 4;
  const v8s z8 = {0, 0, 0, 0, 0, 0, 0, 0};

  for (int task = blockIdx.x; task < tasks; task += gridDim.x) {
    const int w = task / NH, hh = task - w * NH;
    int vox_i = NVOX;
    if (lane < cap) vox_i = idx[w * cap + lane];
    vox_lds[lane] = vox_i;
    __syncthreads();

    // stage Q,K: 48 rows x 8 chunks of 8 bf16; lane covers (row, chunk)
#pragma unroll
    for (int it = 0; it < 6; ++it) {
      int id = it * 64 + lane;  // 0..383
      int j = id >> 3, c = id & 7;
      int vj = vox_lds[j];
      v8s q8 = z8, k8 = z8;
      if (vj < NVOX) {
        const unsigned short* base = qkv + (size_t)vj * (3 * CCH) + hh * DH + c * 8;
        q8 = *(const v8s*)(base);
        k8 = *(const v8s*)(base + CCH);
      }
      *(v8s*)(QP + j * APITCH + c * 8) = q8;
      *(v8s*)(Ks + j * APITCH + c * 8) = k8;
    }
    // stage V transposed: lane = d, column j
#pragma unroll 4
    for (int j = 0; j < CAP; ++j) {
      int vj = vox_lds[j];
      unsigned short vv = 0;
      if (vj < NVOX) vv = qkv[(size_t)vj * (3 * CCH) + 2 * CCH + hh * DH + lane];
      Vt[lane * APITCH + j] = vv;
    }
#pragma unroll
    for (int j = CAP; j < 64; ++j) Vt[lane * APITCH + j] = 0;  // k-padding
    __syncthreads();

    // S = Q . K^T  (rows i, cols j)
    v4f s_acc[3][3];
#pragma unroll
    for (int mi = 0; mi < 3; ++mi)
#pragma unroll
      for (int jt = 0; jt < 3; ++jt) s_acc[mi][jt] = (v4f){0.f, 0.f, 0.f, 0.f};
#pragma unroll
    for (int ks = 0; ks < 2; ++ks) {
      v8s qf[3], kf[3];
#pragma unroll
      for (int mi = 0; mi < 3; ++mi)
        qf[mi] = *(const v8s*)(QP + (mi * 16 + fm) * APITCH + ks * 32 + fq * 8);
#pragma unroll
      for (int jt = 0; jt < 3; ++jt)
        kf[jt] = *(const v8s*)(Ks + (jt * 16 + fm) * APITCH + ks * 32 + fq * 8);
#pragma unroll
      for (int mi = 0; mi < 3; ++mi)
#pragma unroll
        for (int jt = 0; jt < 3; ++jt)
          s_acc[mi][jt] = __builtin_amdgcn_mfma_f32_16x16x32_bf16(qf[mi], kf[jt], s_acc[mi][jt], 0, 0, 0);
    }
    __syncthreads();  // Q fragment reads complete before P overwrites QP

    // masked softmax in C-layout registers; scale 1/8 folded into exp,
    // 1/den folded into P. Scores are O(1) here -> exp without max-subtract.
    bool va0 = (fm < cap) && (vox_lds[fm] < NVOX);
    bool va1 = (16 + fm < cap) && (vox_lds[16 + fm] < NVOX);
    bool va2 = (32 + fm < cap) && (vox_lds[32 + fm] < NVOX);
#pragma unroll
    for (int mi = 0; mi < 3; ++mi) {
#pragma unroll
      for (int r = 0; r < 4; ++r) {
        float e0 = va0 ? __expf(s_acc[mi][0][r] * 0.125f) : 0.f;
        float e1 = va1 ? __expf(s_acc[mi][1][r] * 0.125f) : 0.f;
        float e2 = va2 ? __expf(s_acc[mi][2][r] * 0.125f) : 0.f;
        float den = e0 + e1 + e2;
        den += __shfl_xor(den, 1, 64);
        den += __shfl_xor(den, 2, 64);
        den += __shfl_xor(den, 4, 64);
        den += __shfl_xor(den, 8, 64);
        float rden = (den > 0.f) ? 1.0f / den : 0.f;
        int row = mi * 16 + fq * 4 + r;
        QP[row * APITCH + fm] = f2bf(e0 * rden);
        QP[row * APITCH + 16 + fm] = f2bf(e1 * rden);
        QP[row * APITCH + 32 + fm] = f2bf(e2 * rden);
      }
    }
    if (lane < CAP) {  // zero P cols 48..64 (k padding for PV)
      *(v8s*)(QP + lane * APITCH + 48) = z8;
      *(v8s*)(QP + lane * APITCH + 56) = z8;
    }
    __syncthreads();

    // O = P . V   (rows i, cols d)
    v4f o_acc[3][4];
#pragma unroll
    for (int mi = 0; mi < 3; ++mi)
#pragma unroll
      for (int nt = 0; nt < 4; ++nt) o_acc[mi][nt] = (v4f){0.f, 0.f, 0.f, 0.f};
#pragma unroll
    for (int ks = 0; ks < 2; ++ks) {
      v8s pf[3], vf[4];
#pragma unroll
      for (int mi = 0; mi < 3; ++mi)
        pf[mi] = *(const v8s*)(QP + (mi * 16 + fm) * APITCH + ks * 32 + fq * 8);
#pragma unroll
      for (int nt = 0; nt < 4; ++nt)
        vf[nt] = *(const v8s*)(Vt + (nt * 16 + fm) * APITCH + ks * 32 + fq * 8);
#pragma unroll
      for (int mi = 0; mi < 3; ++mi)
#pragma unroll
        for (int nt = 0; nt < 4; ++nt)
          o_acc[mi][nt] = __builtin_amdgcn_mfma_f32_16x16x32_bf16(pf[mi], vf[nt], o_acc[mi][nt], 0, 0, 0);
    }

    // scatter store O rows
#pragma unroll
    for (int mi = 0; mi < 3; ++mi) {
#pragma unroll
      for (int r = 0; r < 4; ++r) {
        int i = mi * 16 + fq * 4 + r;
        int vox = vox_lds[i];
        if (i < cap && vox < NVOX) {
          unsigned short* ob = attn_out + (size_t)vox * CCH + hh * DH + fm;
#pragma unroll
          for (int nt = 0; nt < 4; ++nt) ob[nt * 16] = f2bf(o_acc[mi][nt][r]);
        }
      }
    }
    __syncthreads();  // P/Vt reads done before next task's staging
  }
}

// ---------------------------------------------------------------------------
// gaussian decode: reads padded [N][512] fp32, writes d_out [N][448]
// ---------------------------------------------------------------------------
__global__ __launch_bounds__(256) void decode_kernel(const float* __restrict__ outpad,
                                                     const int* __restrict__ coords,
                                                     const float* __restrict__ perturb,
                                                     float* __restrict__ out) {
  __shared__ float row[OUT_CH];
  const int n = blockIdx.x;
  const float* src = outpad + (size_t)n * OUT_PAD;
  for (int e = threadIdx.x; e < OUT_CH; e += 256) row[e] = src[e];
  __syncthreads();
  float* o = out + (size_t)n * OUT_CH;
  for (int e = threadIdx.x; e < OUT_CH; e += 256) {
    int g = e / 14, j = e - g * 14;
    float v;
    if (j < 3) {
      float xyz = ((float)coords[n * 3 + j] + 0.5f) * (1.0f / 64.0f);
      v = xyz + tanhf(row[g * 3 + j] + perturb[g * 3 + j]) * (0.75f / 64.0f);
    } else if (j < 6) {
      v = row[96 + g * 3 + (j - 3)];
    } else if (j < 9) {
      v = row[192 + g * 3 + (j - 6)];
    } else if (j < 13) {
      v = row[288 + g * 4 + (j - 9)] * 0.1f;
    } else {
      v = row[416 + g];
    }
    o[e] = v;
  }
}

// ---------------------------------------------------------------------------
extern "C" void kernel_launch(void* const* d_in, const int* in_sizes, int n_in,
                              void* d_out, int out_size, void* d_ws, size_t ws_size,
                              hipStream_t stream) {
  const float* feats = (const float*)d_in[0];
  const int* coords = (const int*)d_in[1];
  const float* in_w = (const float*)d_in[2];
  const float* in_b = (const float*)d_in[3];
  const float* qkv_w = (const float*)d_in[4];
  const float* qkv_b = (const float*)d_in[5];
  const float* proj_w = (const float*)d_in[6];
  const float* proj_b = (const float*)d_in[7];
  const float* mlp_w1 = (const float*)d_in[8];
  const float* mlp_b1 = (const float*)d_in[9];
  const float* mlp_w2 = (const float*)d_in[10];
  const float* mlp_b2 = (const float*)d_in[11];
  const float* out_w = (const float*)d_in[12];
  const float* out_b = (const float*)d_in[13];
  const float* perturb = (const float*)d_in[14];
  const int* idx0 = (const int*)d_in[15];
  const int* vslot0 = (const int*)d_in[18];
  const int* idx1 = (const int*)d_in[19];
  const int* vslot1 = (const int*)d_in[22];
  const int total0 = in_sizes[15];
  const int total1 = in_sizes[19];

  char* p = (char*)d_ws;
  int* caps = (int*)p;                                                    // 256 B
  float* h = (float*)(p + 256);                                           // 25165824
  unsigned short* abuf = (unsigned short*)(p + 256 + 25165824);           // 12582912
  unsigned short* big = (unsigned short*)(p + 256 + 37748736);            // 50331648
  unsigned short* wst = (unsigned short*)(p + 256 + 88080384);            // 14155776
  float* outpad = (float*)(p + 256 + 102236160);                          // 16777216
  const size_t OQ = 0;
  const size_t OP = (size_t)768 * 2304;
  const size_t OM1 = OP + (size_t)768 * 768;
  const size_t OM2 = OM1 + (size_t)768 * 3072;

  cap_kernel<<<1, 256, 0, stream>>>(vslot0, vslot1, NVOX, caps);
  embed_kernel<<<(NVOX * CCH + 255) / 256, 256, 0, stream>>>(feats, coords, in_w, in_b, h);

  for (int i = 0; i < NBLK; ++i) {
    const int* idx = (i & 1) ? idx1 : idx0;
    const int* capP = (i & 1) ? caps + 1 : caps;
    const int total = (i & 1) ? total1 : total0;

    wconvert4<<<1728, 256, 0, stream>>>(
        qkv_w + (size_t)i * 768 * 2304, proj_w + (size_t)i * 768 * 768,
        mlp_w1 + (size_t)i * 768 * 3072, mlp_w2 + (size_t)i * 3072 * 768,
        wst + OQ, wst + OP, wst + OM1, wst + OM2);

    ln_kernel<<<NVOX, 256, 0, stream>>>(h, abuf, 1e-6f);
    gemm_mfma<0, 0, 1><<<dim3(18, 64), 256, 0, stream>>>(
        abuf, wst + OQ, qkv_b + (size_t)i * 2304, 2304, nullptr, big, 2304, 768);
    attn_kernel<<<4096, 64, 0, stream>>>(big, idx, capP, total, abuf);
    gemm_mfma<0, 1, 0><<<dim3(6, 64), 256, 0, stream>>>(
        abuf, wst + OP, proj_b + (size_t)i * 768, 768, h, nullptr, 768, 768);
    ln_kernel<<<NVOX, 256, 0, stream>>>(h, abuf, 1e-6f);
    gemm_mfma<1, 0, 1><<<dim3(24, 64), 256, 0, stream>>>(
        abuf, wst + OM1, mlp_b1 + (size_t)i * 3072, 3072, nullptr, big, 3072, 768);
    gemm_mfma<0, 1, 0><<<dim3(6, 64), 256, 0, stream>>>(
        big, wst + OM2, mlp_b2 + (size_t)i * 768, 768, h, nullptr, 768, 3072);
  }

  ln_kernel<<<NVOX, 256, 0, stream>>>(h, abuf, 1e-5f);
  wconvert<<<dim3(8, 12), 256, 0, stream>>>(out_w, wst + OQ, 768, OUT_CH);
  gemm_mfma<0, 0, 0><<<dim3(4, 64), 256, 0, stream>>>(
      abuf, wst + OQ, out_b, OUT_CH, outpad, nullptr, OUT_PAD, 768);
  decode_kernel<<<NVOX, 256, 0, stream>>>(outpad, coords, perturb, (float*)d_out);
}

// Round 3
// 4135.352 us; speedup vs baseline: 1.1731x; 1.0641x over previous
//
#include <hip/hip_runtime.h>
#include <math.h>

#define NVOX 8192
#define CCH 768
#define NH 12
#define DH 64
#define NBLK 12
#define NG 32
#define OUT_CH 448
#define OUT_PAD 512
#define CAP 48
#define APITCH 72  // LDS row pitch (bf16) for Q/K/P/Vt: 144 B rows, 16B-aligned
#define PIPE 3     // GEMM pipeline depth (LDS K-tile buffers in flight)

typedef __attribute__((ext_vector_type(8))) short v8s;
typedef __attribute__((ext_vector_type(4))) float v4f;

__device__ __forceinline__ unsigned short f2bf(float f) {
  unsigned u = __builtin_bit_cast(unsigned, f);
  u += 0x7fffu + ((u >> 16) & 1u);  // RNE
  return (unsigned short)(u >> 16);
}
__device__ __forceinline__ float bf2f(unsigned short b) {
  return __builtin_bit_cast(float, (unsigned)b << 16);
}

__device__ __forceinline__ void async16(const void* g, void* l) {
  __builtin_amdgcn_global_load_lds(
      (const __attribute__((address_space(1))) unsigned int*)g,
      (__attribute__((address_space(3))) unsigned int*)l, 16, 0, 0);
}

// ---------------------------------------------------------------------------
// prep: cap = max(vslot)+1 for both window configs
// ---------------------------------------------------------------------------
__global__ __launch_bounds__(256) void cap_kernel(const int* __restrict__ a,
                                                  const int* __restrict__ b,
                                                  int n, int* __restrict__ caps) {
  __shared__ int s0[256], s1[256];
  int m0 = 0, m1 = 0;
  for (int i = threadIdx.x; i < n; i += 256) {
    m0 = max(m0, a[i]);
    m1 = max(m1, b[i]);
  }
  s0[threadIdx.x] = m0;
  s1[threadIdx.x] = m1;
  __syncthreads();
  for (int st = 128; st > 0; st >>= 1) {
    if (threadIdx.x < st) {
      s0[threadIdx.x] = max(s0[threadIdx.x], s0[threadIdx.x + st]);
      s1[threadIdx.x] = max(s1[threadIdx.x], s1[threadIdx.x + st]);
    }
    __syncthreads();
  }
  if (threadIdx.x == 0) {
    caps[0] = s0[0] + 1;
    caps[1] = s1[0] + 1;
  }
}

// ---------------------------------------------------------------------------
// embed: h = feats @ in_w + in_b + pos_embed(coords)   (fp32 residual stream)
// ---------------------------------------------------------------------------
__global__ __launch_bounds__(256) void embed_kernel(const float* __restrict__ feats,
                                                    const int* __restrict__ coords,
                                                    const float* __restrict__ in_w,
                                                    const float* __restrict__ in_b,
                                                    float* __restrict__ h) {
  int id = blockIdx.x * 256 + threadIdx.x;
  if (id >= NVOX * CCH) return;
  int n = id / CCH, c = id - n * CCH;
  float acc = in_b[c];
#pragma unroll
  for (int k = 0; k < 8; ++k) acc += feats[n * 8 + k] * in_w[k * CCH + c];
  int axis = c / 256;
  int r = c - axis * 256;
  int f = r & 127;
  float freq = __expf(-(float)f * (9.210340371976184f / 128.0f));  // ln(10000)
  float phase = (float)coords[n * 3 + axis] * freq;
  acc += (r < 128) ? __sinf(phase) : __cosf(phase);
  h[id] = acc;
}

// ---------------------------------------------------------------------------
// layernorm (no affine) -> bf16 output (A-operand of following GEMM)
// ---------------------------------------------------------------------------
__global__ __launch_bounds__(256) void ln_kernel(const float* __restrict__ x,
                                                 unsigned short* __restrict__ y,
                                                 float eps) {
  int row = blockIdx.x;
  const float* xr = x + (size_t)row * CCH;
  float v[3];
  float s = 0.f, s2 = 0.f;
#pragma unroll
  for (int j = 0; j < 3; ++j) {
    v[j] = xr[threadIdx.x + j * 256];
    s += v[j];
    s2 += v[j] * v[j];
  }
#pragma unroll
  for (int off = 32; off >= 1; off >>= 1) {
    s += __shfl_xor(s, off, 64);
    s2 += __shfl_xor(s2, off, 64);
  }
  __shared__ float ss[4], ss2[4];
  int wave = threadIdx.x >> 6, lane = threadIdx.x & 63;
  if (lane == 0) { ss[wave] = s; ss2[wave] = s2; }
  __syncthreads();
  s = ss[0] + ss[1] + ss[2] + ss[3];
  s2 = ss2[0] + ss2[1] + ss2[2] + ss2[3];
  float mu = s * (1.0f / CCH);
  float var = s2 * (1.0f / CCH) - mu * mu;
  float rr = rsqrtf(var + eps);
  unsigned short* yr = y + (size_t)row * CCH;
#pragma unroll
  for (int j = 0; j < 3; ++j) yr[threadIdx.x + j * 256] = f2bf((v[j] - mu) * rr);
}

// ---------------------------------------------------------------------------
// weight convert: W fp32 [K][Nsrc] -> Wt bf16 [N][K] (transposed; n>=Nsrc -> 0)
// ---------------------------------------------------------------------------
__device__ __forceinline__ void wconv_tile(const float* __restrict__ W,
                                           unsigned short* __restrict__ Wt,
                                           int K, int Nsrc, int nt, int kt,
                                           float (*t)[65]) {
  int n0 = nt * 64, k0 = kt * 64;
  for (int e = threadIdx.x; e < 4096; e += 256) {
    int r = e >> 6, c = e & 63;
    int n = n0 + c;
    t[r][c] = (n < Nsrc) ? W[(size_t)(k0 + r) * Nsrc + n] : 0.f;
  }
  __syncthreads();
  for (int e = threadIdx.x; e < 4096; e += 256) {
    int rn = e >> 6, ck = e & 63;
    Wt[(size_t)(n0 + rn) * K + k0 + ck] = f2bf(t[ck][rn]);
  }
}

__global__ __launch_bounds__(256) void wconvert(const float* __restrict__ W,
                                                unsigned short* __restrict__ Wt,
                                                int K, int Nsrc) {
  __shared__ float t[64][65];
  wconv_tile(W, Wt, K, Nsrc, blockIdx.x, blockIdx.y, t);
}

// fused: all 4 weights of one block in one launch (1728 tiles)
__global__ __launch_bounds__(256) void wconvert4(const float* __restrict__ W0,
                                                 const float* __restrict__ W1,
                                                 const float* __restrict__ W2,
                                                 const float* __restrict__ W3,
                                                 unsigned short* __restrict__ D0,
                                                 unsigned short* __restrict__ D1,
                                                 unsigned short* __restrict__ D2,
                                                 unsigned short* __restrict__ D3) {
  __shared__ float t[64][65];
  int b = blockIdx.x;
  if (b < 432) {
    wconv_tile(W0, D0, 768, 2304, b / 12, b % 12, t);        // qkv 768x2304
  } else if (b < 576) {
    b -= 432;
    wconv_tile(W1, D1, 768, 768, b / 12, b % 12, t);         // proj 768x768
  } else if (b < 1152) {
    b -= 576;
    wconv_tile(W2, D2, 768, 3072, b / 12, b % 12, t);        // mlp1 768x3072
  } else {
    b -= 1152;
    wconv_tile(W3, D3, 3072, 768, b / 48, b % 48, t);        // mlp2 3072x768
  }
}

// ---------------------------------------------------------------------------
// bf16 MFMA GEMM, 3-deep counted-vmcnt pipeline (T3+T4):
//   3 LDS K-tile buffers; raw s_barrier + s_waitcnt vmcnt(8) keeps tiles
//   t+1,t+2 in flight ACROSS barriers (never drains to 0 in the loop).
//   Per iter: vmcnt(8) -> barrier (tile t landed) -> ds_read -> lgkmcnt(0)
//   -> barrier (all reads done, buffer reusable) -> issue tile t+PIPE -> MFMA.
// LDS XOR chunk swizzle (T2, rule #21): linear gload_lds dest, inverse-
//   swizzled GLOBAL source (chunk c^(row&3)), swizzled ds_read offset.
//   Cuts 8-way bank conflict on the fragment reads to 4-way.
// out[M,Nn] = act(A[M,K] @ Bt[Nn,K]^T + bias); XCD-bijective tile swizzle.
// ---------------------------------------------------------------------------
__device__ __forceinline__ float gelu_exact(float x) {
  return 0.5f * x * (1.0f + erff(x * 0.70710678118654752f));
}

template <int ACT, int RES, int OUTBF>
__global__ __launch_bounds__(256) void gemm_mfma(const unsigned short* __restrict__ A,
                                                 const unsigned short* __restrict__ Bt,
                                                 const float* __restrict__ bias, int Nbias,
                                                 float* __restrict__ outf,
                                                 unsigned short* __restrict__ outb,
                                                 int Nn, int K) {
  __shared__ __align__(16) unsigned short As[PIPE][128 * 32];
  __shared__ __align__(16) unsigned short Bs[PIPE][128 * 32];
  const int tid = threadIdx.x;
  const int lane = tid & 63, w = tid >> 6;

  // m204 bijective XCD swizzle on the (x,y) tile grid
  int bx = blockIdx.x, by = blockIdx.y;
  {
    const int gx = gridDim.x, gy = gridDim.y;
    const int nwg = gx * gy;
    const int id = by * gx + bx;
    const int q = nwg >> 3, r = nwg & 7;
    const int xc = id & 7, off = id >> 3;
    const int nid = (xc < r ? xc * (q + 1) : r * (q + 1) + (xc - r) * q) + off;
    bx = nid % gx;
    by = nid / gx;
  }
  const int row0 = by * 128, col0 = bx * 128;
  const int wm = (w >> 1) * 64, wn = (w & 1) * 64;
  const int fm = lane & 15, fq = lane >> 4;

  // staging: lane covers LDS slot (r, c) linearly; global source pre-swizzled
  // so slot (r, c) holds global chunk c ^ (r & 3)
  const int c0 = w * 64 + lane;
  const int c1 = c0 + 256;
  const int r0s = c0 >> 2, ch0 = (c0 & 3) ^ (r0s & 3);
  const int r1s = c1 >> 2, ch1 = (c1 & 3) ^ (r1s & 3);
  const unsigned short* gA0 = A + (size_t)(row0 + r0s) * K + ch0 * 8;
  const unsigned short* gA1 = A + (size_t)(row0 + r1s) * K + ch1 * 8;
  const unsigned short* gB0 = Bt + (size_t)(col0 + r0s) * K + ch0 * 8;
  const unsigned short* gB1 = Bt + (size_t)(col0 + r1s) * K + ch1 * 8;
  const int oL0 = w * 512;         // shorts; linear dest, rows 0..63 strip
  const int oL1 = w * 512 + 2048;  // rows 64..127 strip
  // swizzled fragment-read chunk offset: row & 3 == fm & 3 for all fragments
  const int xo = ((fq ^ (fm & 3)) * 8);

  v4f acc[4][4];
#pragma unroll
  for (int i = 0; i < 4; ++i)
#pragma unroll
    for (int j = 0; j < 4; ++j) acc[i][j] = (v4f){0.f, 0.f, 0.f, 0.f};

  const int NT = K >> 5;
  // prologue: stage tiles 0..PIPE-1 (12 loads in flight per wave)
#pragma unroll
  for (int t = 0; t < PIPE; ++t) {
    const int k0 = t * 32;
    async16(gA0 + k0, (unsigned short*)As + t * 4096 + oL0);
    async16(gA1 + k0, (unsigned short*)As + t * 4096 + oL1);
    async16(gB0 + k0, (unsigned short*)Bs + t * 4096 + oL0);
    async16(gB1 + k0, (unsigned short*)Bs + t * 4096 + oL1);
  }

  int buf = 0;
  int kpf = PIPE * 32;  // k-offset (shorts) of next prefetch
  for (int t = 0; t < NT; ++t) {
    unsigned short* Ab = (unsigned short*)As + buf * 4096;
    unsigned short* Bb = (unsigned short*)Bs + buf * 4096;
    // tile t's 4 loads complete for every wave (8 = tiles t+1,t+2 in flight)
    asm volatile("s_waitcnt vmcnt(8)" ::: "memory");
    __builtin_amdgcn_s_barrier();
    v8s af[4], bfv[4];
#pragma unroll
    for (int i = 0; i < 4; ++i)
      af[i] = *(const v8s*)(Ab + (wm + i * 16 + fm) * 32 + xo);
#pragma unroll
    for (int j = 0; j < 4; ++j)
      bfv[j] = *(const v8s*)(Bb + (wn + j * 16 + fm) * 32 + xo);
    // my ds_reads complete -> barrier -> all waves' reads complete:
    // buffer safe to overwrite with the next prefetch
    asm volatile("s_waitcnt lgkmcnt(0)" ::: "memory");
    __builtin_amdgcn_s_barrier();
    {
      // tail (kpf >= K): redundant reload of the current tile keeps the
      // vmcnt accounting uniform; data identical so overwrite is benign
      const int kq = (kpf < K) ? kpf : (kpf - PIPE * 32);
      async16(gA0 + kq, Ab + oL0);
      async16(gA1 + kq, Ab + oL1);
      async16(gB0 + kq, Bb + oL0);
      async16(gB1 + kq, Bb + oL1);
    }
#pragma unroll
    for (int i = 0; i < 4; ++i)
#pragma unroll
      for (int j = 0; j < 4; ++j)
        acc[i][j] = __builtin_amdgcn_mfma_f32_16x16x32_bf16(af[i], bfv[j], acc[i][j], 0, 0, 0);
    kpf += 32;
    buf = (buf == PIPE - 1) ? 0 : buf + 1;
  }

#pragma unroll
  for (int i = 0; i < 4; ++i) {
    int row = row0 + wm + i * 16 + fq * 4;
#pragma unroll
    for (int j = 0; j < 4; ++j) {
      int col = col0 + wn + j * 16 + fm;
      float b = (col < Nbias) ? bias[col] : 0.f;
#pragma unroll
      for (int r = 0; r < 4; ++r) {
        float v = acc[i][j][r] + b;
        if (ACT == 1) v = gelu_exact(v);
        size_t o = (size_t)(row + r) * Nn + col;
        if (RES) {
          outf[o] += v;
        } else if (OUTBF) {
          outb[o] = f2bf(v);
        } else {
          outf[o] = v;
        }
      }
    }
  }
}

// ---------------------------------------------------------------------------
// MFMA windowed attention: one wave per (window, head).
// S = Q.K^T (3x3 tiles of 16x16x32), in-register masked softmax (rden folded),
// P (bf16, aliased over Q) . V -> O (3x4 tiles), scatter bf16 store.
// ---------------------------------------------------------------------------
__global__ __launch_bounds__(64) void attn_kernel(const unsigned short* __restrict__ qkv,
                                                  const int* __restrict__ idx,
                                                  const int* __restrict__ capPtr,
                                                  int total,
                                                  unsigned short* __restrict__ attn_out) {
  __shared__ __align__(16) unsigned short QP[CAP * APITCH];  // Q, then P
  __shared__ __align__(16) unsigned short Ks[CAP * APITCH];
  __shared__ __align__(16) unsigned short Vt[64 * APITCH];   // V transposed [d][j]
  __shared__ int vox_lds[64];
  const int cap = *capPtr;
  if (cap > CAP) return;  // loud failure rather than OOB
  const int nw = total / cap;
  const int tasks = nw * NH;
  const int lane = threadIdx.x;
  const int fm = lane & 15, fq = lane >> 4;
  const v8s z8 = {0, 0, 0, 0, 0, 0, 0, 0};

  for (int task = blockIdx.x; task < tasks; task += gridDim.x) {
    const int w = task / NH, hh = task - w * NH;
    int vox_i = NVOX;
    if (lane < cap) vox_i = idx[w * cap + lane];
    vox_lds[lane] = vox_i;
    __syncthreads();

    // stage Q,K: 48 rows x 8 chunks of 8 bf16; lane covers (row, chunk)
#pragma unroll
    for (int it = 0; it < 6; ++it) {
      int id = it * 64 + lane;  // 0..383
      int j = id >> 3, c = id & 7;
      int vj = vox_lds[j];
      v8s q8 = z8, k8 = z8;
      if (vj < NVOX) {
        const unsigned short* base = qkv + (size_t)vj * (3 * CCH) + hh * DH + c * 8;
        q8 = *(const v8s*)(base);
        k8 = *(const v8s*)(base + CCH);
      }
      *(v8s*)(QP + j * APITCH + c * 8) = q8;
      *(v8s*)(Ks + j * APITCH + c * 8) = k8;
    }
    // stage V transposed: lane = d, column j
#pragma unroll 4
    for (int j = 0; j < CAP; ++j) {
      int vj = vox_lds[j];
      unsigned short vv = 0;
      if (vj < NVOX) vv = qkv[(size_t)vj * (3 * CCH) + 2 * CCH + hh * DH + lane];
      Vt[lane * APITCH + j] = vv;
    }
#pragma unroll
    for (int j = CAP; j < 64; ++j) Vt[lane * APITCH + j] = 0;  // k-padding
    __syncthreads();

    // S = Q . K^T  (rows i, cols j)
    v4f s_acc[3][3];
#pragma unroll
    for (int mi = 0; mi < 3; ++mi)
#pragma unroll
      for (int jt = 0; jt < 3; ++jt) s_acc[mi][jt] = (v4f){0.f, 0.f, 0.f, 0.f};
#pragma unroll
    for (int ks = 0; ks < 2; ++ks) {
      v8s qf[3], kf[3];
#pragma unroll
      for (int mi = 0; mi < 3; ++mi)
        qf[mi] = *(const v8s*)(QP + (mi * 16 + fm) * APITCH + ks * 32 + fq * 8);
#pragma unroll
      for (int jt = 0; jt < 3; ++jt)
        kf[jt] = *(const v8s*)(Ks + (jt * 16 + fm) * APITCH + ks * 32 + fq * 8);
#pragma unroll
      for (int mi = 0; mi < 3; ++mi)
#pragma unroll
        for (int jt = 0; jt < 3; ++jt)
          s_acc[mi][jt] = __builtin_amdgcn_mfma_f32_16x16x32_bf16(qf[mi], kf[jt], s_acc[mi][jt], 0, 0, 0);
    }
    __syncthreads();  // Q fragment reads complete before P overwrites QP

    // masked softmax in C-layout registers; scale 1/8 folded into exp,
    // 1/den folded into P. Scores are O(1) here -> exp without max-subtract.
    bool va0 = (fm < cap) && (vox_lds[fm] < NVOX);
    bool va1 = (16 + fm < cap) && (vox_lds[16 + fm] < NVOX);
    bool va2 = (32 + fm < cap) && (vox_lds[32 + fm] < NVOX);
#pragma unroll
    for (int mi = 0; mi < 3; ++mi) {
#pragma unroll
      for (int r = 0; r < 4; ++r) {
        float e0 = va0 ? __expf(s_acc[mi][0][r] * 0.125f) : 0.f;
        float e1 = va1 ? __expf(s_acc[mi][1][r] * 0.125f) : 0.f;
        float e2 = va2 ? __expf(s_acc[mi][2][r] * 0.125f) : 0.f;
        float den = e0 + e1 + e2;
        den += __shfl_xor(den, 1, 64);
        den += __shfl_xor(den, 2, 64);
        den += __shfl_xor(den, 4, 64);
        den += __shfl_xor(den, 8, 64);
        float rden = (den > 0.f) ? 1.0f / den : 0.f;
        int row = mi * 16 + fq * 4 + r;
        QP[row * APITCH + fm] = f2bf(e0 * rden);
        QP[row * APITCH + 16 + fm] = f2bf(e1 * rden);
        QP[row * APITCH + 32 + fm] = f2bf(e2 * rden);
      }
    }
    if (lane < CAP) {  // zero P cols 48..64 (k padding for PV)
      *(v8s*)(QP + lane * APITCH + 48) = z8;
      *(v8s*)(QP + lane * APITCH + 56) = z8;
    }
    __syncthreads();

    // O = P . V   (rows i, cols d)
    v4f o_acc[3][4];
#pragma unroll
    for (int mi = 0; mi < 3; ++mi)
#pragma unroll
      for (int nt = 0; nt < 4; ++nt) o_acc[mi][nt] = (v4f){0.f, 0.f, 0.f, 0.f};
#pragma unroll
    for (int ks = 0; ks < 2; ++ks) {
      v8s pf[3], vf[4];
#pragma unroll
      for (int mi = 0; mi < 3; ++mi)
        pf[mi] = *(const v8s*)(QP + (mi * 16 + fm) * APITCH + ks * 32 + fq * 8);
#pragma unroll
      for (int nt = 0; nt < 4; ++nt)
        vf[nt] = *(const v8s*)(Vt + (nt * 16 + fm) * APITCH + ks * 32 + fq * 8);
#pragma unroll
      for (int mi = 0; mi < 3; ++mi)
#pragma unroll
        for (int nt = 0; nt < 4; ++nt)
          o_acc[mi][nt] = __builtin_amdgcn_mfma_f32_16x16x32_bf16(pf[mi], vf[nt], o_acc[mi][nt], 0, 0, 0);
    }

    // scatter store O rows
#pragma unroll
    for (int mi = 0; mi < 3; ++mi) {
#pragma unroll
      for (int r = 0; r < 4; ++r) {
        int i = mi * 16 + fq * 4 + r;
        int vox = vox_lds[i];
        if (i < cap && vox < NVOX) {
          unsigned short* ob = attn_out + (size_t)vox * CCH + hh * DH + fm;
#pragma unroll
          for (int nt = 0; nt < 4; ++nt) ob[nt * 16] = f2bf(o_acc[mi][nt][r]);
        }
      }
    }
    __syncthreads();  // P/Vt reads done before next task's staging
  }
}

// ---------------------------------------------------------------------------
// gaussian decode: reads padded [N][512] fp32, writes d_out [N][448]
// ---------------------------------------------------------------------------
__global__ __launch_bounds__(256) void decode_kernel(const float* __restrict__ outpad,
                                                     const int* __restrict__ coords,
                                                     const float* __restrict__ perturb,
                                                     float* __restrict__ out) {
  __shared__ float row[OUT_CH];
  const int n = blockIdx.x;
  const float* src = outpad + (size_t)n * OUT_PAD;
  for (int e = threadIdx.x; e < OUT_CH; e += 256) row[e] = src[e];
  __syncthreads();
  float* o = out + (size_t)n * OUT_CH;
  for (int e = threadIdx.x; e < OUT_CH; e += 256) {
    int g = e / 14, j = e - g * 14;
    float v;
    if (j < 3) {
      float xyz = ((float)coords[n * 3 + j] + 0.5f) * (1.0f / 64.0f);
      v = xyz + tanhf(row[g * 3 + j] + perturb[g * 3 + j]) * (0.75f / 64.0f);
    } else if (j < 6) {
      v = row[96 + g * 3 + (j - 3)];
    } else if (j < 9) {
      v = row[192 + g * 3 + (j - 6)];
    } else if (j < 13) {
      v = row[288 + g * 4 + (j - 9)] * 0.1f;
    } else {
      v = row[416 + g];
    }
    o[e] = v;
  }
}

// ---------------------------------------------------------------------------
extern "C" void kernel_launch(void* const* d_in, const int* in_sizes, int n_in,
                              void* d_out, int out_size, void* d_ws, size_t ws_size,
                              hipStream_t stream) {
  const float* feats = (const float*)d_in[0];
  const int* coords = (const int*)d_in[1];
  const float* in_w = (const float*)d_in[2];
  const float* in_b = (const float*)d_in[3];
  const float* qkv_w = (const float*)d_in[4];
  const float* qkv_b = (const float*)d_in[5];
  const float* proj_w = (const float*)d_in[6];
  const float* proj_b = (const float*)d_in[7];
  const float* mlp_w1 = (const float*)d_in[8];
  const float* mlp_b1 = (const float*)d_in[9];
  const float* mlp_w2 = (const float*)d_in[10];
  const float* mlp_b2 = (const float*)d_in[11];
  const float* out_w = (const float*)d_in[12];
  const float* out_b = (const float*)d_in[13];
  const float* perturb = (const float*)d_in[14];
  const int* idx0 = (const int*)d_in[15];
  const int* vslot0 = (const int*)d_in[18];
  const int* idx1 = (const int*)d_in[19];
  const int* vslot1 = (const int*)d_in[22];
  const int total0 = in_sizes[15];
  const int total1 = in_sizes[19];

  char* p = (char*)d_ws;
  int* caps = (int*)p;                                                    // 256 B
  float* h = (float*)(p + 256);                                           // 25165824
  unsigned short* abuf = (unsigned short*)(p + 256 + 25165824);           // 12582912
  unsigned short* big = (unsigned short*)(p + 256 + 37748736);            // 50331648
  unsigned short* wst = (unsigned short*)(p + 256 + 88080384);            // 14155776
  float* outpad = (float*)(p + 256 + 102236160);                          // 16777216
  const size_t OQ = 0;
  const size_t OP = (size_t)768 * 2304;
  const size_t OM1 = OP + (size_t)768 * 768;
  const size_t OM2 = OM1 + (size_t)768 * 3072;

  cap_kernel<<<1, 256, 0, stream>>>(vslot0, vslot1, NVOX, caps);
  embed_kernel<<<(NVOX * CCH + 255) / 256, 256, 0, stream>>>(feats, coords, in_w, in_b, h);

  for (int i = 0; i < NBLK; ++i) {
    const int* idx = (i & 1) ? idx1 : idx0;
    const int* capP = (i & 1) ? caps + 1 : caps;
    const int total = (i & 1) ? total1 : total0;

    wconvert4<<<1728, 256, 0, stream>>>(
        qkv_w + (size_t)i * 768 * 2304, proj_w + (size_t)i * 768 * 768,
        mlp_w1 + (size_t)i * 768 * 3072, mlp_w2 + (size_t)i * 3072 * 768,
        wst + OQ, wst + OP, wst + OM1, wst + OM2);

    ln_kernel<<<NVOX, 256, 0, stream>>>(h, abuf, 1e-6f);
    gemm_mfma<0, 0, 1><<<dim3(18, 64), 256, 0, stream>>>(
        abuf, wst + OQ, qkv_b + (size_t)i * 2304, 2304, nullptr, big, 2304, 768);
    attn_kernel<<<4096, 64, 0, stream>>>(big, idx, capP, total, abuf);
    gemm_mfma<0, 1, 0><<<dim3(6, 64), 256, 0, stream>>>(
        abuf, wst + OP, proj_b + (size_t)i * 768, 768, h, nullptr, 768, 768);
    ln_kernel<<<NVOX, 256, 0, stream>>>(h, abuf, 1e-6f);
    gemm_mfma<1, 0, 1><<<dim3(24, 64), 256, 0, stream>>>(
        abuf, wst + OM1, mlp_b1 + (size_t)i * 3072, 3072, nullptr, big, 3072, 768);
    gemm_mfma<0, 1, 0><<<dim3(6, 64), 256, 0, stream>>>(
        big, wst + OM2, mlp_b2 + (size_t)i * 768, 768, h, nullptr, 768, 3072);
  }

  ln_kernel<<<NVOX, 256, 0, stream>>>(h, abuf, 1e-5f);
  wconvert<<<dim3(8, 12), 256, 0, stream>>>(out_w, wst + OQ, 768, OUT_CH);
  gemm_mfma<0, 0, 0><<<dim3(4, 64), 256, 0, stream>>>(
      abuf, wst + OQ, out_b, OUT_CH, outpad, nullptr, OUT_PAD, 768);
  decode_kernel<<<NVOX, 256, 0, stream>>>(outpad, coords, perturb, (float*)d_out);
}

// Round 5
// 4002.884 us; speedup vs baseline: 1.2119x; 1.0331x over previous
//
#include <hip/hip_runtime.h>
#include <math.h>

#define NVOX 8192
#define CCH 768
#define NH 12
#define DH 64
#define NBLK 12
#define NG 32
#define OUT_CH 448
#define OUT_PAD 512
#define CAP 48
#define APITCH 72  // LDS row pitch (bf16) for P/Vt rows: 144 B, 16B-aligned

typedef __attribute__((ext_vector_type(8))) short v8s;
typedef __attribute__((ext_vector_type(4))) float v4f;

__device__ __forceinline__ unsigned short f2bf(float f) {
  unsigned u = __builtin_bit_cast(unsigned, f);
  u += 0x7fffu + ((u >> 16) & 1u);  // RNE
  return (unsigned short)(u >> 16);
}
__device__ __forceinline__ float bf2f(unsigned short b) {
  return __builtin_bit_cast(float, (unsigned)b << 16);
}

__device__ __forceinline__ void async16(const void* g, void* l) {
  __builtin_amdgcn_global_load_lds(
      (const __attribute__((address_space(1))) unsigned int*)g,
      (__attribute__((address_space(3))) unsigned int*)l, 16, 0, 0);
}

// ---------------------------------------------------------------------------
// prep: cap = max(vslot)+1 for both window configs
// ---------------------------------------------------------------------------
__global__ __launch_bounds__(256) void cap_kernel(const int* __restrict__ a,
                                                  const int* __restrict__ b,
                                                  int n, int* __restrict__ caps) {
  __shared__ int s0[256], s1[256];
  int m0 = 0, m1 = 0;
  for (int i = threadIdx.x; i < n; i += 256) {
    m0 = max(m0, a[i]);
    m1 = max(m1, b[i]);
  }
  s0[threadIdx.x] = m0;
  s1[threadIdx.x] = m1;
  __syncthreads();
  for (int st = 128; st > 0; st >>= 1) {
    if (threadIdx.x < st) {
      s0[threadIdx.x] = max(s0[threadIdx.x], s0[threadIdx.x + st]);
      s1[threadIdx.x] = max(s1[threadIdx.x], s1[threadIdx.x + st]);
    }
    __syncthreads();
  }
  if (threadIdx.x == 0) {
    caps[0] = s0[0] + 1;
    caps[1] = s1[0] + 1;
  }
}

// ---------------------------------------------------------------------------
// embed: h = feats @ in_w + in_b + pos_embed(coords)   (fp32 residual stream)
// ---------------------------------------------------------------------------
__global__ __launch_bounds__(256) void embed_kernel(const float* __restrict__ feats,
                                                    const int* __restrict__ coords,
                                                    const float* __restrict__ in_w,
                                                    const float* __restrict__ in_b,
                                                    float* __restrict__ h) {
  int id = blockIdx.x * 256 + threadIdx.x;
  if (id >= NVOX * CCH) return;
  int n = id / CCH, c = id - n * CCH;
  float acc = in_b[c];
#pragma unroll
  for (int k = 0; k < 8; ++k) acc += feats[n * 8 + k] * in_w[k * CCH + c];
  int axis = c / 256;
  int r = c - axis * 256;
  int f = r & 127;
  float freq = __expf(-(float)f * (9.210340371976184f / 128.0f));  // ln(10000)
  float phase = (float)coords[n * 3 + axis] * freq;
  acc += (r < 128) ? __sinf(phase) : __cosf(phase);
  h[id] = acc;
}

// ---------------------------------------------------------------------------
// layernorm (no affine) -> bf16 output (A-operand of following GEMM)
// ---------------------------------------------------------------------------
__global__ __launch_bounds__(256) void ln_kernel(const float* __restrict__ x,
                                                 unsigned short* __restrict__ y,
                                                 float eps) {
  int row = blockIdx.x;
  const float* xr = x + (size_t)row * CCH;
  float v[3];
  float s = 0.f, s2 = 0.f;
#pragma unroll
  for (int j = 0; j < 3; ++j) {
    v[j] = xr[threadIdx.x + j * 256];
    s += v[j];
    s2 += v[j] * v[j];
  }
#pragma unroll
  for (int off = 32; off >= 1; off >>= 1) {
    s += __shfl_xor(s, off, 64);
    s2 += __shfl_xor(s2, off, 64);
  }
  __shared__ float ss[4], ss2[4];
  int wave = threadIdx.x >> 6, lane = threadIdx.x & 63;
  if (lane == 0) { ss[wave] = s; ss2[wave] = s2; }
  __syncthreads();
  s = ss[0] + ss[1] + ss[2] + ss[3];
  s2 = ss2[0] + ss2[1] + ss2[2] + ss2[3];
  float mu = s * (1.0f / CCH);
  float var = s2 * (1.0f / CCH) - mu * mu;
  float rr = rsqrtf(var + eps);
  unsigned short* yr = y + (size_t)row * CCH;
#pragma unroll
  for (int j = 0; j < 3; ++j) yr[threadIdx.x + j * 256] = f2bf((v[j] - mu) * rr);
}

// ---------------------------------------------------------------------------
// weight convert: W fp32 [K][Nsrc] -> Wt bf16 [N][K] (transposed; n>=Nsrc -> 0)
// ---------------------------------------------------------------------------
__device__ __forceinline__ void wconv_tile(const float* __restrict__ W,
                                           unsigned short* __restrict__ Wt,
                                           int K, int Nsrc, int nt, int kt,
                                           float (*t)[65]) {
  int n0 = nt * 64, k0 = kt * 64;
  for (int e = threadIdx.x; e < 4096; e += 256) {
    int r = e >> 6, c = e & 63;
    int n = n0 + c;
    t[r][c] = (n < Nsrc) ? W[(size_t)(k0 + r) * Nsrc + n] : 0.f;
  }
  __syncthreads();
  for (int e = threadIdx.x; e < 4096; e += 256) {
    int rn = e >> 6, ck = e & 63;
    Wt[(size_t)(n0 + rn) * K + k0 + ck] = f2bf(t[ck][rn]);
  }
}

__global__ __launch_bounds__(256) void wconvert(const float* __restrict__ W,
                                                unsigned short* __restrict__ Wt,
                                                int K, int Nsrc) {
  __shared__ float t[64][65];
  wconv_tile(W, Wt, K, Nsrc, blockIdx.x, blockIdx.y, t);
}

// fused: all 4 weights of one block in one launch (1728 tiles)
__global__ __launch_bounds__(256) void wconvert4(const float* __restrict__ W0,
                                                 const float* __restrict__ W1,
                                                 const float* __restrict__ W2,
                                                 const float* __restrict__ W3,
                                                 unsigned short* __restrict__ D0,
                                                 unsigned short* __restrict__ D1,
                                                 unsigned short* __restrict__ D2,
                                                 unsigned short* __restrict__ D3) {
  __shared__ float t[64][65];
  int b = blockIdx.x;
  if (b < 432) {
    wconv_tile(W0, D0, 768, 2304, b / 12, b % 12, t);        // qkv 768x2304
  } else if (b < 576) {
    b -= 432;
    wconv_tile(W1, D1, 768, 768, b / 12, b % 12, t);         // proj 768x768
  } else if (b < 1152) {
    b -= 576;
    wconv_tile(W2, D2, 768, 3072, b / 12, b % 12, t);        // mlp1 768x3072
  } else {
    b -= 1152;
    wconv_tile(W3, D3, 3072, 768, b / 48, b % 48, t);        // mlp2 3072x768
  }
}

// ---------------------------------------------------------------------------
// bf16 MFMA GEMM, PIPE-deep counted-vmcnt pipeline, statically unrolled:
//   buffer indices + all LDS/global offsets are compile-time immediates;
//   pointers advance once per group of PIPE K-steps. vmcnt((PIPE-1)*4)
//   keeps PIPE-1 tiles in flight across barriers (never drains in-loop).
//   HARDENING: explicit vmcnt(0) drain before epilogue — a wave must not
//   reach s_endpgm with LDS-DMA writes outstanding (freed-LDS corruption).
// out[M,Nn] = act(A[M,K] @ Bt[Nn,K]^T + bias); XCD-bijective tile swizzle.
// ---------------------------------------------------------------------------
__device__ __forceinline__ float gelu_exact(float x) {
  return 0.5f * x * (1.0f + erff(x * 0.70710678118654752f));
}

template <int ACT, int RES, int OUTBF, int PIPE>
__global__ __launch_bounds__(256) void gemm_mfma(const unsigned short* __restrict__ A,
                                                 const unsigned short* __restrict__ Bt,
                                                 const float* __restrict__ bias, int Nbias,
                                                 float* __restrict__ outf,
                                                 unsigned short* __restrict__ outb,
                                                 int Nn, int K) {
  __shared__ __align__(16) unsigned short As[PIPE * 4096];
  __shared__ __align__(16) unsigned short Bs[PIPE * 4096];
  const int tid = threadIdx.x;
  const int lane = tid & 63, w = tid >> 6;

  // m204 bijective XCD swizzle on the (x,y) tile grid
  int bx = blockIdx.x, by = blockIdx.y;
  {
    const int gx = gridDim.x, gy = gridDim.y;
    const int nwg = gx * gy;
    const int id = by * gx + bx;
    const int q = nwg >> 3, r = nwg & 7;
    const int xc = id & 7, off = id >> 3;
    const int nid = (xc < r ? xc * (q + 1) : r * (q + 1) + (xc - r) * q) + off;
    bx = nid % gx;
    by = nid / gx;
  }
  const int row0 = by * 128, col0 = bx * 128;
  const int wm = (w >> 1) * 64, wn = (w & 1) * 64;
  const int fm = lane & 15, fq = lane >> 4;

  const int c0 = w * 64 + lane;
  const int c1 = c0 + 256;
  const unsigned short* pA0 = A + (size_t)(row0 + (c0 >> 2)) * K + (c0 & 3) * 8;
  const unsigned short* pA1 = A + (size_t)(row0 + (c1 >> 2)) * K + (c1 & 3) * 8;
  const unsigned short* pB0 = Bt + (size_t)(col0 + (c0 >> 2)) * K + (c0 & 3) * 8;
  const unsigned short* pB1 = Bt + (size_t)(col0 + (c1 >> 2)) * K + (c1 & 3) * 8;
  const int oL0 = w * 512;         // shorts; rows 0..63 strip
  const int oL1 = w * 512 + 2048;  // rows 64..127 strip

  v4f acc[4][4];
#pragma unroll
  for (int i = 0; i < 4; ++i)
#pragma unroll
    for (int j = 0; j < 4; ++j) acc[i][j] = (v4f){0.f, 0.f, 0.f, 0.f};

  // prologue: stage tiles 0..PIPE-1 (static offsets)
#pragma unroll
  for (int u = 0; u < PIPE; ++u) {
    async16(pA0 + u * 32, As + u * 4096 + oL0);
    async16(pA1 + u * 32, As + u * 4096 + oL1);
    async16(pB0 + u * 32, Bs + u * 4096 + oL0);
    async16(pB1 + u * 32, Bs + u * 4096 + oL1);
  }

#define GEMM_STEP(U, POFS)                                                      \
  {                                                                             \
    if constexpr (PIPE == 4) {                                                  \
      asm volatile("s_waitcnt vmcnt(12)" ::: "memory");                         \
    } else {                                                                    \
      asm volatile("s_waitcnt vmcnt(8)" ::: "memory");                          \
    }                                                                           \
    __builtin_amdgcn_s_barrier();                                               \
    v8s af[4], bfv[4];                                                          \
    _Pragma("unroll") for (int i = 0; i < 4; ++i)                               \
        af[i] = *(const v8s*)(As + (U)*4096 + (wm + i * 16 + fm) * 32 + fq * 8);\
    _Pragma("unroll") for (int j = 0; j < 4; ++j)                               \
        bfv[j] = *(const v8s*)(Bs + (U)*4096 + (wn + j * 16 + fm) * 32 + fq * 8);\
    asm volatile("s_waitcnt lgkmcnt(0)" ::: "memory");                          \
    __builtin_amdgcn_s_barrier();                                               \
    async16(pA0 + (POFS), As + (U)*4096 + oL0);                                 \
    async16(pA1 + (POFS), As + (U)*4096 + oL1);                                 \
    async16(pB0 + (POFS), Bs + (U)*4096 + oL0);                                 \
    async16(pB1 + (POFS), Bs + (U)*4096 + oL1);                                 \
    _Pragma("unroll") for (int i = 0; i < 4; ++i)                               \
        _Pragma("unroll") for (int j = 0; j < 4; ++j)                           \
            acc[i][j] =                                                         \
        __builtin_amdgcn_mfma_f32_16x16x32_bf16(af[i], bfv[j], acc[i][j], 0, 0, 0); \
  }

  const int NGRP = K / (32 * PIPE);
  for (int g = 0; g < NGRP - 1; ++g) {
#pragma unroll
    for (int u = 0; u < PIPE; ++u) GEMM_STEP(u, (u + PIPE) * 32)
    pA0 += PIPE * 32;
    pA1 += PIPE * 32;
    pB0 += PIPE * 32;
    pB1 += PIPE * 32;
  }
  // last group: prefetch slots re-load the current tiles (uniform vmcnt flow)
#pragma unroll
  for (int u = 0; u < PIPE; ++u) GEMM_STEP(u, u * 32)
#undef GEMM_STEP

  // drain all outstanding LDS-DMA before any wave can reach s_endpgm:
  // in-flight global_load_lds writes into deallocated LDS corrupt other blocks
  asm volatile("s_waitcnt vmcnt(0)" ::: "memory");
  __builtin_amdgcn_s_barrier();

#pragma unroll
  for (int i = 0; i < 4; ++i) {
    int row = row0 + wm + i * 16 + fq * 4;
#pragma unroll
    for (int j = 0; j < 4; ++j) {
      int col = col0 + wn + j * 16 + fm;
      float b = (col < Nbias) ? bias[col] : 0.f;
#pragma unroll
      for (int r = 0; r < 4; ++r) {
        float v = acc[i][j][r] + b;
        if (ACT == 1) v = gelu_exact(v);
        size_t o = (size_t)(row + r) * Nn + col;
        if (RES) {
          outf[o] += v;
        } else if (OUTBF) {
          outb[o] = f2bf(v);
        } else {
          outf[o] = v;
        }
      }
    }
  }
}

// ---------------------------------------------------------------------------
// MFMA windowed attention: one wave per (window, head).
// Q,K fragments gathered DIRECTLY to registers (no LDS staging, no barrier);
// V staged row-major (6 coalesced v8s iters) then transposed in LDS.
// S = Q.K^T (3x3), in-register masked softmax (rden folded), P.V -> O.
// LDS: P(48x72) + Vt(64x72) + vox = 16.4 KB -> 9 blocks/CU (was 23 KB / 6).
// ---------------------------------------------------------------------------
__global__ __launch_bounds__(64) void attn_kernel(const unsigned short* __restrict__ qkv,
                                                  const int* __restrict__ idx,
                                                  const int* __restrict__ capPtr,
                                                  int total,
                                                  unsigned short* __restrict__ attn_out) {
  __shared__ __align__(16) unsigned short Pb[CAP * APITCH];  // V-rows, then P
  __shared__ __align__(16) unsigned short Vt[64 * APITCH];   // V transposed [d][j]
  __shared__ int vox_lds[64];
  const int cap = *capPtr;
  if (cap > CAP) return;  // loud failure rather than OOB
  const int nw = total / cap;
  const int tasks = nw * NH;
  const int lane = threadIdx.x;
  const int fm = lane & 15, fq = lane >> 4;
  const v8s z8 = {0, 0, 0, 0, 0, 0, 0, 0};

  for (int task = blockIdx.x; task < tasks; task += gridDim.x) {
    const int w = task / NH, hh = task - w * NH;
    int vox_i = NVOX;
    if (lane < cap) vox_i = idx[w * cap + lane];
    vox_lds[lane] = vox_i;
    __syncthreads();

    // stage V rows into Pb: 48 rows x 8 chunks of 8 bf16 (coalesced-ish v8s)
#pragma unroll
    for (int it = 0; it < 6; ++it) {
      int id = it * 64 + lane;  // 0..383
      int j = id >> 3, c = id & 7;
      int vj = vox_lds[j];
      v8s v8 = z8;
      if (vj < NVOX)
        v8 = *(const v8s*)(qkv + (size_t)vj * (3 * CCH) + 2 * CCH + hh * DH + c * 8);
      *(v8s*)(Pb + j * APITCH + c * 8) = v8;
    }

    // gather Q,K fragments directly to registers (rows mi*16+fm, k = ks*32+fq*8)
    v8s qf[3][2], kf[3][2];
#pragma unroll
    for (int mi = 0; mi < 3; ++mi) {
      int row = mi * 16 + fm;
      int vj = (row < cap) ? vox_lds[row] : NVOX;
      const unsigned short* base = qkv + (size_t)vj * (3 * CCH) + hh * DH + fq * 8;
#pragma unroll
      for (int ks = 0; ks < 2; ++ks) {
        qf[mi][ks] = (vj < NVOX) ? *(const v8s*)(base + ks * 32) : z8;
        kf[mi][ks] = (vj < NVOX) ? *(const v8s*)(base + CCH + ks * 32) : z8;
      }
    }

    // S = Q . K^T  (register-only)
    v4f s_acc[3][3];
#pragma unroll
    for (int mi = 0; mi < 3; ++mi)
#pragma unroll
      for (int jt = 0; jt < 3; ++jt) s_acc[mi][jt] = (v4f){0.f, 0.f, 0.f, 0.f};
#pragma unroll
    for (int ks = 0; ks < 2; ++ks)
#pragma unroll
      for (int mi = 0; mi < 3; ++mi)
#pragma unroll
        for (int jt = 0; jt < 3; ++jt)
          s_acc[mi][jt] = __builtin_amdgcn_mfma_f32_16x16x32_bf16(qf[mi][ks], kf[jt][ks], s_acc[mi][jt], 0, 0, 0);

    __syncthreads();  // V rows staged
    // transpose Pb (rows j, cols d) -> Vt (rows d, cols j); lane = column j
    if (lane < CAP) {
#pragma unroll
      for (int c = 0; c < 8; ++c) {
        v8s r8 = *(const v8s*)(Pb + lane * APITCH + c * 8);
#pragma unroll
        for (int e = 0; e < 8; ++e) Vt[(c * 8 + e) * APITCH + lane] = r8[e];
      }
    } else {
#pragma unroll
      for (int d = 0; d < 64; ++d) Vt[d * APITCH + lane] = 0;  // j-padding
    }
    __syncthreads();  // transpose reads of Pb done; P may overwrite

    // masked softmax in C-layout registers; scale 1/8 folded into exp,
    // 1/den folded into P. Scores are O(1) here -> exp without max-subtract.
    bool va0 = (fm < cap) && (vox_lds[fm] < NVOX);
    bool va1 = (16 + fm < cap) && (vox_lds[16 + fm] < NVOX);
    bool va2 = (32 + fm < cap) && (vox_lds[32 + fm] < NVOX);
#pragma unroll
    for (int mi = 0; mi < 3; ++mi) {
#pragma unroll
      for (int r = 0; r < 4; ++r) {
        float e0 = va0 ? __expf(s_acc[mi][0][r] * 0.125f) : 0.f;
        float e1 = va1 ? __expf(s_acc[mi][1][r] * 0.125f) : 0.f;
        float e2 = va2 ? __expf(s_acc[mi][2][r] * 0.125f) : 0.f;
        float den = e0 + e1 + e2;
        den += __shfl_xor(den, 1, 64);
        den += __shfl_xor(den, 2, 64);
        den += __shfl_xor(den, 4, 64);
        den += __shfl_xor(den, 8, 64);
        float rden = (den > 0.f) ? 1.0f / den : 0.f;
        int row = mi * 16 + fq * 4 + r;
        Pb[row * APITCH + fm] = f2bf(e0 * rden);
        Pb[row * APITCH + 16 + fm] = f2bf(e1 * rden);
        Pb[row * APITCH + 32 + fm] = f2bf(e2 * rden);
      }
    }
    if (lane < CAP) {  // zero P cols 48..64 (k padding for PV)
      *(v8s*)(Pb + lane * APITCH + 48) = z8;
      *(v8s*)(Pb + lane * APITCH + 56) = z8;
    }
    __syncthreads();

    // O = P . V   (rows i, cols d)
    v4f o_acc[3][4];
#pragma unroll
    for (int mi = 0; mi < 3; ++mi)
#pragma unroll
      for (int nt = 0; nt < 4; ++nt) o_acc[mi][nt] = (v4f){0.f, 0.f, 0.f, 0.f};
#pragma unroll
    for (int ks = 0; ks < 2; ++ks) {
      v8s pf[3], vf[4];
#pragma unroll
      for (int mi = 0; mi < 3; ++mi)
        pf[mi] = *(const v8s*)(Pb + (mi * 16 + fm) * APITCH + ks * 32 + fq * 8);
#pragma unroll
      for (int nt = 0; nt < 4; ++nt)
        vf[nt] = *(const v8s*)(Vt + (nt * 16 + fm) * APITCH + ks * 32 + fq * 8);
#pragma unroll
      for (int mi = 0; mi < 3; ++mi)
#pragma unroll
        for (int nt = 0; nt < 4; ++nt)
          o_acc[mi][nt] = __builtin_amdgcn_mfma_f32_16x16x32_bf16(pf[mi], vf[nt], o_acc[mi][nt], 0, 0, 0);
    }

    // scatter store O rows
#pragma unroll
    for (int mi = 0; mi < 3; ++mi) {
#pragma unroll
      for (int r = 0; r < 4; ++r) {
        int i = mi * 16 + fq * 4 + r;
        int vox = vox_lds[i];
        if (i < cap && vox < NVOX) {
          unsigned short* ob = attn_out + (size_t)vox * CCH + hh * DH + fm;
#pragma unroll
          for (int nt = 0; nt < 4; ++nt) ob[nt * 16] = f2bf(o_acc[mi][nt][r]);
        }
      }
    }
    __syncthreads();  // Pb/Vt reads done before next task's staging
  }
}

// ---------------------------------------------------------------------------
// gaussian decode: reads padded [N][512] fp32, writes d_out [N][448]
// ---------------------------------------------------------------------------
__global__ __launch_bounds__(256) void decode_kernel(const float* __restrict__ outpad,
                                                     const int* __restrict__ coords,
                                                     const float* __restrict__ perturb,
                                                     float* __restrict__ out) {
  __shared__ float row[OUT_CH];
  const int n = blockIdx.x;
  const float* src = outpad + (size_t)n * OUT_PAD;
  for (int e = threadIdx.x; e < OUT_CH; e += 256) row[e] = src[e];
  __syncthreads();
  float* o = out + (size_t)n * OUT_CH;
  for (int e = threadIdx.x; e < OUT_CH; e += 256) {
    int g = e / 14, j = e - g * 14;
    float v;
    if (j < 3) {
      float xyz = ((float)coords[n * 3 + j] + 0.5f) * (1.0f / 64.0f);
      v = xyz + tanhf(row[g * 3 + j] + perturb[g * 3 + j]) * (0.75f / 64.0f);
    } else if (j < 6) {
      v = row[96 + g * 3 + (j - 3)];
    } else if (j < 9) {
      v = row[192 + g * 3 + (j - 6)];
    } else if (j < 13) {
      v = row[288 + g * 4 + (j - 9)] * 0.1f;
    } else {
      v = row[416 + g];
    }
    o[e] = v;
  }
}

// ---------------------------------------------------------------------------
extern "C" void kernel_launch(void* const* d_in, const int* in_sizes, int n_in,
                              void* d_out, int out_size, void* d_ws, size_t ws_size,
                              hipStream_t stream) {
  const float* feats = (const float*)d_in[0];
  const int* coords = (const int*)d_in[1];
  const float* in_w = (const float*)d_in[2];
  const float* in_b = (const float*)d_in[3];
  const float* qkv_w = (const float*)d_in[4];
  const float* qkv_b = (const float*)d_in[5];
  const float* proj_w = (const float*)d_in[6];
  const float* proj_b = (const float*)d_in[7];
  const float* mlp_w1 = (const float*)d_in[8];
  const float* mlp_b1 = (const float*)d_in[9];
  const float* mlp_w2 = (const float*)d_in[10];
  const float* mlp_b2 = (const float*)d_in[11];
  const float* out_w = (const float*)d_in[12];
  const float* out_b = (const float*)d_in[13];
  const float* perturb = (const float*)d_in[14];
  const int* idx0 = (const int*)d_in[15];
  const int* vslot0 = (const int*)d_in[18];
  const int* idx1 = (const int*)d_in[19];
  const int* vslot1 = (const int*)d_in[22];
  const int total0 = in_sizes[15];
  const int total1 = in_sizes[19];

  char* p = (char*)d_ws;
  int* caps = (int*)p;                                                    // 256 B
  float* h = (float*)(p + 256);                                           // 25165824
  unsigned short* abuf = (unsigned short*)(p + 256 + 25165824);           // 12582912
  unsigned short* big = (unsigned short*)(p + 256 + 37748736);            // 50331648
  unsigned short* wst = (unsigned short*)(p + 256 + 88080384);            // 14155776
  float* outpad = (float*)(p + 256 + 102236160);                          // 16777216
  const size_t OQ = 0;
  const size_t OP = (size_t)768 * 2304;
  const size_t OM1 = OP + (size_t)768 * 768;
  const size_t OM2 = OM1 + (size_t)768 * 3072;

  cap_kernel<<<1, 256, 0, stream>>>(vslot0, vslot1, NVOX, caps);
  embed_kernel<<<(NVOX * CCH + 255) / 256, 256, 0, stream>>>(feats, coords, in_w, in_b, h);

  for (int i = 0; i < NBLK; ++i) {
    const int* idx = (i & 1) ? idx1 : idx0;
    const int* capP = (i & 1) ? caps + 1 : caps;
    const int total = (i & 1) ? total1 : total0;

    wconvert4<<<1728, 256, 0, stream>>>(
        qkv_w + (size_t)i * 768 * 2304, proj_w + (size_t)i * 768 * 768,
        mlp_w1 + (size_t)i * 768 * 3072, mlp_w2 + (size_t)i * 3072 * 768,
        wst + OQ, wst + OP, wst + OM1, wst + OM2);

    ln_kernel<<<NVOX, 256, 0, stream>>>(h, abuf, 1e-6f);
    gemm_mfma<0, 0, 1, 3><<<dim3(18, 64), 256, 0, stream>>>(
        abuf, wst + OQ, qkv_b + (size_t)i * 2304, 2304, nullptr, big, 2304, 768);
    attn_kernel<<<4096, 64, 0, stream>>>(big, idx, capP, total, abuf);
    gemm_mfma<0, 1, 0, 4><<<dim3(6, 64), 256, 0, stream>>>(
        abuf, wst + OP, proj_b + (size_t)i * 768, 768, h, nullptr, 768, 768);
    ln_kernel<<<NVOX, 256, 0, stream>>>(h, abuf, 1e-6f);
    gemm_mfma<1, 0, 1, 3><<<dim3(24, 64), 256, 0, stream>>>(
        abuf, wst + OM1, mlp_b1 + (size_t)i * 3072, 3072, nullptr, big, 3072, 768);
    gemm_mfma<0, 1, 0, 4><<<dim3(6, 64), 256, 0, stream>>>(
        big, wst + OM2, mlp_b2 + (size_t)i * 768, 768, h, nullptr, 768, 3072);
  }

  ln_kernel<<<NVOX, 256, 0, stream>>>(h, abuf, 1e-5f);
  wconvert<<<dim3(8, 12), 256, 0, stream>>>(out_w, wst + OQ, 768, OUT_CH);
  gemm_mfma<0, 0, 0, 4><<<dim3(4, 64), 256, 0, stream>>>(
      abuf, wst + OQ, out_b, OUT_CH, outpad, nullptr, OUT_PAD, 768);
  decode_kernel<<<NVOX, 256, 0, stream>>>(outpad, coords, perturb, (float*)d_out);
}

// Round 7
// 3697.915 us; speedup vs baseline: 1.3118x; 1.0825x over previous
//
#include <hip/hip_runtime.h>
#include <math.h>

#define NVOX 8192
#define CCH 768
#define NH 12
#define DH 64
#define NBLK 12
#define NG 32
#define OUT_CH 448
#define OUT_PAD 512
#define CAP 48
#define APITCH 72  // LDS row pitch (bf16) for P/Vt rows: 144 B, 16B-aligned

typedef __attribute__((ext_vector_type(8))) short v8s;
typedef __attribute__((ext_vector_type(4))) float v4f;

__device__ __forceinline__ unsigned short f2bf(float f) {
  unsigned u = __builtin_bit_cast(unsigned, f);
  u += 0x7fffu + ((u >> 16) & 1u);  // RNE
  return (unsigned short)(u >> 16);
}
__device__ __forceinline__ float bf2f(unsigned short b) {
  return __builtin_bit_cast(float, (unsigned)b << 16);
}

__device__ __forceinline__ void async16(const void* g, void* l) {
  __builtin_amdgcn_global_load_lds(
      (const __attribute__((address_space(1))) unsigned int*)g,
      (__attribute__((address_space(3))) unsigned int*)l, 16, 0, 0);
}

// ---------------------------------------------------------------------------
// prep: cap = max(vslot)+1 for both window configs
// ---------------------------------------------------------------------------
__global__ __launch_bounds__(256) void cap_kernel(const int* __restrict__ a,
                                                  const int* __restrict__ b,
                                                  int n, int* __restrict__ caps) {
  __shared__ int s0[256], s1[256];
  int m0 = 0, m1 = 0;
  for (int i = threadIdx.x; i < n; i += 256) {
    m0 = max(m0, a[i]);
    m1 = max(m1, b[i]);
  }
  s0[threadIdx.x] = m0;
  s1[threadIdx.x] = m1;
  __syncthreads();
  for (int st = 128; st > 0; st >>= 1) {
    if (threadIdx.x < st) {
      s0[threadIdx.x] = max(s0[threadIdx.x], s0[threadIdx.x + st]);
      s1[threadIdx.x] = max(s1[threadIdx.x], s1[threadIdx.x + st]);
    }
    __syncthreads();
  }
  if (threadIdx.x == 0) {
    caps[0] = s0[0] + 1;
    caps[1] = s1[0] + 1;
  }
}

// ---------------------------------------------------------------------------
// embed: h = feats @ in_w + in_b + pos_embed(coords)   (fp32 residual stream)
// ---------------------------------------------------------------------------
__global__ __launch_bounds__(256) void embed_kernel(const float* __restrict__ feats,
                                                    const int* __restrict__ coords,
                                                    const float* __restrict__ in_w,
                                                    const float* __restrict__ in_b,
                                                    float* __restrict__ h) {
  int id = blockIdx.x * 256 + threadIdx.x;
  if (id >= NVOX * CCH) return;
  int n = id / CCH, c = id - n * CCH;
  float acc = in_b[c];
#pragma unroll
  for (int k = 0; k < 8; ++k) acc += feats[n * 8 + k] * in_w[k * CCH + c];
  int axis = c / 256;
  int r = c - axis * 256;
  int f = r & 127;
  float freq = __expf(-(float)f * (9.210340371976184f / 128.0f));  // ln(10000)
  float phase = (float)coords[n * 3 + axis] * freq;
  acc += (r < 128) ? __sinf(phase) : __cosf(phase);
  h[id] = acc;
}

// ---------------------------------------------------------------------------
// layernorm (no affine) -> bf16 output (A-operand of following GEMM)
// ---------------------------------------------------------------------------
__global__ __launch_bounds__(256) void ln_kernel(const float* __restrict__ x,
                                                 unsigned short* __restrict__ y,
                                                 float eps) {
  int row = blockIdx.x;
  const float* xr = x + (size_t)row * CCH;
  float v[3];
  float s = 0.f, s2 = 0.f;
#pragma unroll
  for (int j = 0; j < 3; ++j) {
    v[j] = xr[threadIdx.x + j * 256];
    s += v[j];
    s2 += v[j] * v[j];
  }
#pragma unroll
  for (int off = 32; off >= 1; off >>= 1) {
    s += __shfl_xor(s, off, 64);
    s2 += __shfl_xor(s2, off, 64);
  }
  __shared__ float ss[4], ss2[4];
  int wave = threadIdx.x >> 6, lane = threadIdx.x & 63;
  if (lane == 0) { ss[wave] = s; ss2[wave] = s2; }
  __syncthreads();
  s = ss[0] + ss[1] + ss[2] + ss[3];
  s2 = ss2[0] + ss2[1] + ss2[2] + ss2[3];
  float mu = s * (1.0f / CCH);
  float var = s2 * (1.0f / CCH) - mu * mu;
  float rr = rsqrtf(var + eps);
  unsigned short* yr = y + (size_t)row * CCH;
#pragma unroll
  for (int j = 0; j < 3; ++j) yr[threadIdx.x + j * 256] = f2bf((v[j] - mu) * rr);
}

// ---------------------------------------------------------------------------
// weight convert: W fp32 [K][Nsrc] -> Wt bf16 [N][K] (transposed; n>=Nsrc -> 0)
// ---------------------------------------------------------------------------
__device__ __forceinline__ void wconv_tile(const float* __restrict__ W,
                                           unsigned short* __restrict__ Wt,
                                           int K, int Nsrc, int nt, int kt,
                                           float (*t)[65]) {
  int n0 = nt * 64, k0 = kt * 64;
  for (int e = threadIdx.x; e < 4096; e += 256) {
    int r = e >> 6, c = e & 63;
    int n = n0 + c;
    t[r][c] = (n < Nsrc) ? W[(size_t)(k0 + r) * Nsrc + n] : 0.f;
  }
  __syncthreads();
  for (int e = threadIdx.x; e < 4096; e += 256) {
    int rn = e >> 6, ck = e & 63;
    Wt[(size_t)(n0 + rn) * K + k0 + ck] = f2bf(t[ck][rn]);
  }
}

__global__ __launch_bounds__(256) void wconvert(const float* __restrict__ W,
                                                unsigned short* __restrict__ Wt,
                                                int K, int Nsrc) {
  __shared__ float t[64][65];
  wconv_tile(W, Wt, K, Nsrc, blockIdx.x, blockIdx.y, t);
}

// fused: all 4 weights of one block in one launch (1728 tiles)
__global__ __launch_bounds__(256) void wconvert4(const float* __restrict__ W0,
                                                 const float* __restrict__ W1,
                                                 const float* __restrict__ W2,
                                                 const float* __restrict__ W3,
                                                 unsigned short* __restrict__ D0,
                                                 unsigned short* __restrict__ D1,
                                                 unsigned short* __restrict__ D2,
                                                 unsigned short* __restrict__ D3) {
  __shared__ float t[64][65];
  int b = blockIdx.x;
  if (b < 432) {
    wconv_tile(W0, D0, 768, 2304, b / 12, b % 12, t);        // qkv 768x2304
  } else if (b < 576) {
    b -= 432;
    wconv_tile(W1, D1, 768, 768, b / 12, b % 12, t);         // proj 768x768
  } else if (b < 1152) {
    b -= 576;
    wconv_tile(W2, D2, 768, 3072, b / 12, b % 12, t);        // mlp1 768x3072
  } else {
    b -= 1152;
    wconv_tile(W3, D3, 3072, 768, b / 48, b % 48, t);        // mlp2 3072x768
  }
}

// ---------------------------------------------------------------------------
// bf16 MFMA GEMM, PIPE-deep counted-vmcnt pipeline (dynamic loop, r3-best):
//   per step: vmcnt((PIPE-1)*LPT) -> barrier -> ds_read frags -> lgkmcnt(0)
//   -> barrier -> prefetch tile t+PIPE into this buffer -> MFMA.
//   TM=128: 128x128 tile, wave = 64x64 quadrant (grid-rich dispatches).
//   TM=64 : 64x128 tile, wave = 64x32 strip  (grid-starved dispatches:
//           2x blocks at ~same per-step latency -> ~linear speedup).
//   Endpgm hardening: vmcnt(0) drain before epilogue (no in-flight LDS-DMA
//   into deallocated LDS).
// out[M,Nn] = act(A[M,K] @ Bt[Nn,K]^T + bias); XCD-bijective tile swizzle.
// ---------------------------------------------------------------------------
__device__ __forceinline__ float gelu_exact(float x) {
  return 0.5f * x * (1.0f + erff(x * 0.70710678118654752f));
}

template <int ACT, int RES, int OUTBF, int PIPE, int TM>
__global__ __launch_bounds__(256) void gemm_mfma(const unsigned short* __restrict__ A,
                                                 const unsigned short* __restrict__ Bt,
                                                 const float* __restrict__ bias, int Nbias,
                                                 float* __restrict__ outf,
                                                 unsigned short* __restrict__ outb,
                                                 int Nn, int K) {
  constexpr int ATILE = TM * 32;    // shorts per A K-tile
  constexpr int BTILE = 128 * 32;   // shorts per B K-tile
  constexpr int NJ = (TM == 128) ? 4 : 2;
  __shared__ __align__(16) unsigned short As[PIPE * ATILE];
  __shared__ __align__(16) unsigned short Bs[PIPE * BTILE];
  const int tid = threadIdx.x;
  const int lane = tid & 63, w = tid >> 6;

  // m204 bijective XCD swizzle on the (x,y) tile grid
  int bx = blockIdx.x, by = blockIdx.y;
  {
    const int gx = gridDim.x, gy = gridDim.y;
    const int nwg = gx * gy;
    const int id = by * gx + bx;
    const int q = nwg >> 3, r = nwg & 7;
    const int xc = id & 7, off = id >> 3;
    const int nid = (xc < r ? xc * (q + 1) : r * (q + 1) + (xc - r) * q) + off;
    bx = nid % gx;
    by = nid / gx;
  }
  const int row0 = by * TM, col0 = bx * 128;
  const int wm = (TM == 128) ? (w >> 1) * 64 : 0;
  const int wn = (TM == 128) ? (w & 1) * 64 : w * 32;
  const int fm = lane & 15, fq = lane >> 4;

  // staging: thread covers slot c0 (and c0+256 where the tile has 512 slots);
  // slot s = row (s>>2), chunk (s&3). (c0+256) keeps chunk, adds 64 rows.
  const int c0 = w * 64 + lane;
  const unsigned short* pA0 = A + (size_t)(row0 + (c0 >> 2)) * K + (c0 & 3) * 8;
  const unsigned short* pA1 = pA0 + (size_t)64 * K;  // TM=128 only
  const unsigned short* pB0 = Bt + (size_t)(col0 + (c0 >> 2)) * K + (c0 & 3) * 8;
  const unsigned short* pB1 = pB0 + (size_t)64 * K;
  const int oL0 = w * 512;         // shorts; slots 0..255
  const int oL1 = w * 512 + 2048;  // slots 256..511

  v4f acc[4][NJ];
#pragma unroll
  for (int i = 0; i < 4; ++i)
#pragma unroll
    for (int j = 0; j < NJ; ++j) acc[i][j] = (v4f){0.f, 0.f, 0.f, 0.f};

  // prologue: stage tiles 0..PIPE-1
#pragma unroll
  for (int t = 0; t < PIPE; ++t) {
    async16(pA0 + t * 32, As + t * ATILE + oL0);
    if (TM == 128) async16(pA1 + t * 32, As + t * ATILE + oL1);
    async16(pB0 + t * 32, Bs + t * BTILE + oL0);
    async16(pB1 + t * 32, Bs + t * BTILE + oL1);
  }

  const int NT = K >> 5;
  int buf = 0;
  int kpf = PIPE * 32;  // k-offset (shorts) of next prefetch
  for (int t = 0; t < NT; ++t) {
    unsigned short* Ab = As + buf * ATILE;
    unsigned short* Bb = Bs + buf * BTILE;
    // wait until tile t's loads complete for this wave (PIPE-1 tiles stay
    // in flight); barrier -> complete for every wave
    if constexpr (TM == 128) {
      asm volatile("s_waitcnt vmcnt(%0)" ::"i"((PIPE - 1) * 4) : "memory");
    } else {
      asm volatile("s_waitcnt vmcnt(%0)" ::"i"((PIPE - 1) * 3) : "memory");
    }
    __builtin_amdgcn_s_barrier();
    v8s af[4], bfv[NJ];
#pragma unroll
    for (int i = 0; i < 4; ++i)
      af[i] = *(const v8s*)(Ab + (wm + i * 16 + fm) * 32 + fq * 8);
#pragma unroll
    for (int j = 0; j < NJ; ++j)
      bfv[j] = *(const v8s*)(Bb + (wn + j * 16 + fm) * 32 + fq * 8);
    // my ds_reads done -> barrier -> all waves' reads done: buffer reusable
    asm volatile("s_waitcnt lgkmcnt(0)" ::: "memory");
    __builtin_amdgcn_s_barrier();
    {
      // tail (kpf >= K): redundant reload of the current tile keeps the
      // vmcnt accounting uniform; data identical so overwrite is benign
      const int kq = (kpf < K) ? kpf : (kpf - PIPE * 32);
      async16(pA0 + kq, Ab + oL0);
      if (TM == 128) async16(pA1 + kq, Ab + oL1);
      async16(pB0 + kq, Bb + oL0);
      async16(pB1 + kq, Bb + oL1);
    }
#pragma unroll
    for (int i = 0; i < 4; ++i)
#pragma unroll
      for (int j = 0; j < NJ; ++j)
        acc[i][j] = __builtin_amdgcn_mfma_f32_16x16x32_bf16(af[i], bfv[j], acc[i][j], 0, 0, 0);
    kpf += 32;
    buf = (buf == PIPE - 1) ? 0 : buf + 1;
  }

  // drain all outstanding LDS-DMA before any wave can reach s_endpgm:
  // in-flight global_load_lds writes into deallocated LDS corrupt other blocks
  asm volatile("s_waitcnt vmcnt(0)" ::: "memory");
  __builtin_amdgcn_s_barrier();

#pragma unroll
  for (int i = 0; i < 4; ++i) {
    int row = row0 + wm + i * 16 + fq * 4;
#pragma unroll
    for (int j = 0; j < NJ; ++j) {
      int col = col0 + wn + j * 16 + fm;
      float b = (col < Nbias) ? bias[col] : 0.f;
#pragma unroll
      for (int r = 0; r < 4; ++r) {
        float v = acc[i][j][r] + b;
        if (ACT == 1) v = gelu_exact(v);
        size_t o = (size_t)(row + r) * Nn + col;
        if (RES) {
          outf[o] += v;
        } else if (OUTBF) {
          outb[o] = f2bf(v);
        } else {
          outf[o] = v;
        }
      }
    }
  }
}

// ---------------------------------------------------------------------------
// MFMA windowed attention: one wave per (window, head).
// Q,K fragments gathered DIRECTLY to registers (no LDS staging, no barrier);
// V staged row-major (6 coalesced v8s iters) then transposed in LDS.
// S = Q.K^T (3x3), in-register masked softmax (rden folded), P.V -> O.
// LDS: P(48x72) + Vt(64x72) + vox = 16.4 KB -> 9 blocks/CU.
// ---------------------------------------------------------------------------
__global__ __launch_bounds__(64) void attn_kernel(const unsigned short* __restrict__ qkv,
                                                  const int* __restrict__ idx,
                                                  const int* __restrict__ capPtr,
                                                  int total,
                                                  unsigned short* __restrict__ attn_out) {
  __shared__ __align__(16) unsigned short Pb[CAP * APITCH];  // V-rows, then P
  __shared__ __align__(16) unsigned short Vt[64 * APITCH];   // V transposed [d][j]
  __shared__ int vox_lds[64];
  const int cap = *capPtr;
  if (cap > CAP) return;  // loud failure rather than OOB
  const int nw = total / cap;
  const int tasks = nw * NH;
  const int lane = threadIdx.x;
  const int fm = lane & 15, fq = lane >> 4;
  const v8s z8 = {0, 0, 0, 0, 0, 0, 0, 0};

  for (int task = blockIdx.x; task < tasks; task += gridDim.x) {
    const int w = task / NH, hh = task - w * NH;
    int vox_i = NVOX;
    if (lane < cap) vox_i = idx[w * cap + lane];
    vox_lds[lane] = vox_i;
    __syncthreads();

    // stage V rows into Pb: 48 rows x 8 chunks of 8 bf16 (coalesced-ish v8s)
#pragma unroll
    for (int it = 0; it < 6; ++it) {
      int id = it * 64 + lane;  // 0..383
      int j = id >> 3, c = id & 7;
      int vj = vox_lds[j];
      v8s v8 = z8;
      if (vj < NVOX)
        v8 = *(const v8s*)(qkv + (size_t)vj * (3 * CCH) + 2 * CCH + hh * DH + c * 8);
      *(v8s*)(Pb + j * APITCH + c * 8) = v8;
    }

    // gather Q,K fragments directly to registers (rows mi*16+fm, k = ks*32+fq*8)
    v8s qf[3][2], kf[3][2];
#pragma unroll
    for (int mi = 0; mi < 3; ++mi) {
      int row = mi * 16 + fm;
      int vj = (row < cap) ? vox_lds[row] : NVOX;
      const unsigned short* base = qkv + (size_t)vj * (3 * CCH) + hh * DH + fq * 8;
#pragma unroll
      for (int ks = 0; ks < 2; ++ks) {
        qf[mi][ks] = (vj < NVOX) ? *(const v8s*)(base + ks * 32) : z8;
        kf[mi][ks] = (vj < NVOX) ? *(const v8s*)(base + CCH + ks * 32) : z8;
      }
    }

    // S = Q . K^T  (register-only)
    v4f s_acc[3][3];
#pragma unroll
    for (int mi = 0; mi < 3; ++mi)
#pragma unroll
      for (int jt = 0; jt < 3; ++jt) s_acc[mi][jt] = (v4f){0.f, 0.f, 0.f, 0.f};
#pragma unroll
    for (int ks = 0; ks < 2; ++ks)
#pragma unroll
      for (int mi = 0; mi < 3; ++mi)
#pragma unroll
        for (int jt = 0; jt < 3; ++jt)
          s_acc[mi][jt] = __builtin_amdgcn_mfma_f32_16x16x32_bf16(qf[mi][ks], kf[jt][ks], s_acc[mi][jt], 0, 0, 0);

    __syncthreads();  // V rows staged
    // transpose Pb (rows j, cols d) -> Vt (rows d, cols j); lane = column j
    if (lane < CAP) {
#pragma unroll
      for (int c = 0; c < 8; ++c) {
        v8s r8 = *(const v8s*)(Pb + lane * APITCH + c * 8);
#pragma unroll
        for (int e = 0; e < 8; ++e) Vt[(c * 8 + e) * APITCH + lane] = r8[e];
      }
    } else {
#pragma unroll
      for (int d = 0; d < 64; ++d) Vt[d * APITCH + lane] = 0;  // j-padding
    }
    __syncthreads();  // transpose reads of Pb done; P may overwrite

    // masked softmax in C-layout registers; scale 1/8 folded into exp,
    // 1/den folded into P. Scores are O(1) here -> exp without max-subtract.
    bool va0 = (fm < cap) && (vox_lds[fm] < NVOX);
    bool va1 = (16 + fm < cap) && (vox_lds[16 + fm] < NVOX);
    bool va2 = (32 + fm < cap) && (vox_lds[32 + fm] < NVOX);
#pragma unroll
    for (int mi = 0; mi < 3; ++mi) {
#pragma unroll
      for (int r = 0; r < 4; ++r) {
        float e0 = va0 ? __expf(s_acc[mi][0][r] * 0.125f) : 0.f;
        float e1 = va1 ? __expf(s_acc[mi][1][r] * 0.125f) : 0.f;
        float e2 = va2 ? __expf(s_acc[mi][2][r] * 0.125f) : 0.f;
        float den = e0 + e1 + e2;
        den += __shfl_xor(den, 1, 64);
        den += __shfl_xor(den, 2, 64);
        den += __shfl_xor(den, 4, 64);
        den += __shfl_xor(den, 8, 64);
        float rden = (den > 0.f) ? 1.0f / den : 0.f;
        int row = mi * 16 + fq * 4 + r;
        Pb[row * APITCH + fm] = f2bf(e0 * rden);
        Pb[row * APITCH + 16 + fm] = f2bf(e1 * rden);
        Pb[row * APITCH + 32 + fm] = f2bf(e2 * rden);
      }
    }
    if (lane < CAP) {  // zero P cols 48..64 (k padding for PV)
      *(v8s*)(Pb + lane * APITCH + 48) = z8;
      *(v8s*)(Pb + lane * APITCH + 56) = z8;
    }
    __syncthreads();

    // O = P . V   (rows i, cols d)
    v4f o_acc[3][4];
#pragma unroll
    for (int mi = 0; mi < 3; ++mi)
#pragma unroll
      for (int nt = 0; nt < 4; ++nt) o_acc[mi][nt] = (v4f){0.f, 0.f, 0.f, 0.f};
#pragma unroll
    for (int ks = 0; ks < 2; ++ks) {
      v8s pf[3], vf[4];
#pragma unroll
      for (int mi = 0; mi < 3; ++mi)
        pf[mi] = *(const v8s*)(Pb + (mi * 16 + fm) * APITCH + ks * 32 + fq * 8);
#pragma unroll
      for (int nt = 0; nt < 4; ++nt)
        vf[nt] = *(const v8s*)(Vt + (nt * 16 + fm) * APITCH + ks * 32 + fq * 8);
#pragma unroll
      for (int mi = 0; mi < 3; ++mi)
#pragma unroll
        for (int nt = 0; nt < 4; ++nt)
          o_acc[mi][nt] = __builtin_amdgcn_mfma_f32_16x16x32_bf16(pf[mi], vf[nt], o_acc[mi][nt], 0, 0, 0);
    }

    // scatter store O rows
#pragma unroll
    for (int mi = 0; mi < 3; ++mi) {
#pragma unroll
      for (int r = 0; r < 4; ++r) {
        int i = mi * 16 + fq * 4 + r;
        int vox = vox_lds[i];
        if (i < cap && vox < NVOX) {
          unsigned short* ob = attn_out + (size_t)vox * CCH + hh * DH + fm;
#pragma unroll
          for (int nt = 0; nt < 4; ++nt) ob[nt * 16] = f2bf(o_acc[mi][nt][r]);
        }
      }
    }
    __syncthreads();  // Pb/Vt reads done before next task's staging
  }
}

// ---------------------------------------------------------------------------
// gaussian decode: reads padded [N][512] fp32, writes d_out [N][448]
// ---------------------------------------------------------------------------
__global__ __launch_bounds__(256) void decode_kernel(const float* __restrict__ outpad,
                                                     const int* __restrict__ coords,
                                                     const float* __restrict__ perturb,
                                                     float* __restrict__ out) {
  __shared__ float row[OUT_CH];
  const int n = blockIdx.x;
  const float* src = outpad + (size_t)n * OUT_PAD;
  for (int e = threadIdx.x; e < OUT_CH; e += 256) row[e] = src[e];
  __syncthreads();
  float* o = out + (size_t)n * OUT_CH;
  for (int e = threadIdx.x; e < OUT_CH; e += 256) {
    int g = e / 14, j = e - g * 14;
    float v;
    if (j < 3) {
      float xyz = ((float)coords[n * 3 + j] + 0.5f) * (1.0f / 64.0f);
      v = xyz + tanhf(row[g * 3 + j] + perturb[g * 3 + j]) * (0.75f / 64.0f);
    } else if (j < 6) {
      v = row[96 + g * 3 + (j - 3)];
    } else if (j < 9) {
      v = row[192 + g * 3 + (j - 6)];
    } else if (j < 13) {
      v = row[288 + g * 4 + (j - 9)] * 0.1f;
    } else {
      v = row[416 + g];
    }
    o[e] = v;
  }
}

// ---------------------------------------------------------------------------
extern "C" void kernel_launch(void* const* d_in, const int* in_sizes, int n_in,
                              void* d_out, int out_size, void* d_ws, size_t ws_size,
                              hipStream_t stream) {
  const float* feats = (const float*)d_in[0];
  const int* coords = (const int*)d_in[1];
  const float* in_w = (const float*)d_in[2];
  const float* in_b = (const float*)d_in[3];
  const float* qkv_w = (const float*)d_in[4];
  const float* qkv_b = (const float*)d_in[5];
  const float* proj_w = (const float*)d_in[6];
  const float* proj_b = (const float*)d_in[7];
  const float* mlp_w1 = (const float*)d_in[8];
  const float* mlp_b1 = (const float*)d_in[9];
  const float* mlp_w2 = (const float*)d_in[10];
  const float* mlp_b2 = (const float*)d_in[11];
  const float* out_w = (const float*)d_in[12];
  const float* out_b = (const float*)d_in[13];
  const float* perturb = (const float*)d_in[14];
  const int* idx0 = (const int*)d_in[15];
  const int* vslot0 = (const int*)d_in[18];
  const int* idx1 = (const int*)d_in[19];
  const int* vslot1 = (const int*)d_in[22];
  const int total0 = in_sizes[15];
  const int total1 = in_sizes[19];

  char* p = (char*)d_ws;
  int* caps = (int*)p;                                                    // 256 B
  float* h = (float*)(p + 256);                                           // 25165824
  unsigned short* abuf = (unsigned short*)(p + 256 + 25165824);           // 12582912
  unsigned short* big = (unsigned short*)(p + 256 + 37748736);            // 50331648
  unsigned short* wst = (unsigned short*)(p + 256 + 88080384);            // 14155776
  float* outpad = (float*)(p + 256 + 102236160);                          // 16777216
  const size_t OQ = 0;
  const size_t OP = (size_t)768 * 2304;
  const size_t OM1 = OP + (size_t)768 * 768;
  const size_t OM2 = OM1 + (size_t)768 * 3072;

  cap_kernel<<<1, 256, 0, stream>>>(vslot0, vslot1, NVOX, caps);
  embed_kernel<<<(NVOX * CCH + 255) / 256, 256, 0, stream>>>(feats, coords, in_w, in_b, h);

  for (int i = 0; i < NBLK; ++i) {
    const int* idx = (i & 1) ? idx1 : idx0;
    const int* capP = (i & 1) ? caps + 1 : caps;
    const int total = (i & 1) ? total1 : total0;

    wconvert4<<<1728, 256, 0, stream>>>(
        qkv_w + (size_t)i * 768 * 2304, proj_w + (size_t)i * 768 * 768,
        mlp_w1 + (size_t)i * 768 * 3072, mlp_w2 + (size_t)i * 3072 * 768,
        wst + OQ, wst + OP, wst + OM1, wst + OM2);

    ln_kernel<<<NVOX, 256, 0, stream>>>(h, abuf, 1e-6f);
    gemm_mfma<0, 0, 1, 3, 128><<<dim3(18, 64), 256, 0, stream>>>(
        abuf, wst + OQ, qkv_b + (size_t)i * 2304, 2304, nullptr, big, 2304, 768);
    attn_kernel<<<4096, 64, 0, stream>>>(big, idx, capP, total, abuf);
    gemm_mfma<0, 1, 0, 3, 64><<<dim3(6, 128), 256, 0, stream>>>(
        abuf, wst + OP, proj_b + (size_t)i * 768, 768, h, nullptr, 768, 768);
    ln_kernel<<<NVOX, 256, 0, stream>>>(h, abuf, 1e-6f);
    gemm_mfma<1, 0, 1, 3, 128><<<dim3(24, 64), 256, 0, stream>>>(
        abuf, wst + OM1, mlp_b1 + (size_t)i * 3072, 3072, nullptr, big, 3072, 768);
    gemm_mfma<0, 1, 0, 3, 64><<<dim3(6, 128), 256, 0, stream>>>(
        big, wst + OM2, mlp_b2 + (size_t)i * 768, 768, h, nullptr, 768, 3072);
  }

  ln_kernel<<<NVOX, 256, 0, stream>>>(h, abuf, 1e-5f);
  wconvert<<<dim3(8, 12), 256, 0, stream>>>(out_w, wst + OQ, 768, OUT_CH);
  gemm_mfma<0, 0, 0, 3, 64><<<dim3(4, 128), 256, 0, stream>>>(
      abuf, wst + OQ, out_b, OUT_CH, outpad, nullptr, OUT_PAD, 768);
  decode_kernel<<<NVOX, 256, 0, stream>>>(outpad, coords, perturb, (float*)d_out);
}

// Round 9
// 3670.910 us; speedup vs baseline: 1.3215x; 1.0074x over previous
//
#include <hip/hip_runtime.h>
#include <math.h>

#define NVOX 8192
#define CCH 768
#define NH 12
#define DH 64
#define NBLK 12
#define NG 32
#define OUT_CH 448
#define OUT_PAD 512
#define CAP 48
#define APITCH 72  // LDS row pitch (bf16) for P/Vt rows: 144 B, 16B-aligned

typedef __attribute__((ext_vector_type(8))) short v8s;
typedef __attribute__((ext_vector_type(4))) float v4f;

__device__ __forceinline__ unsigned short f2bf(float f) {
  unsigned u = __builtin_bit_cast(unsigned, f);
  u += 0x7fffu + ((u >> 16) & 1u);  // RNE
  return (unsigned short)(u >> 16);
}
__device__ __forceinline__ float bf2f(unsigned short b) {
  return __builtin_bit_cast(float, (unsigned)b << 16);
}

__device__ __forceinline__ void async16(const void* g, void* l) {
  __builtin_amdgcn_global_load_lds(
      (const __attribute__((address_space(1))) unsigned int*)g,
      (__attribute__((address_space(3))) unsigned int*)l, 16, 0, 0);
}

// ---------------------------------------------------------------------------
// prep: cap = max(vslot)+1 for both window configs
// ---------------------------------------------------------------------------
__global__ __launch_bounds__(256) void cap_kernel(const int* __restrict__ a,
                                                  const int* __restrict__ b,
                                                  int n, int* __restrict__ caps) {
  __shared__ int s0[256], s1[256];
  int m0 = 0, m1 = 0;
  for (int i = threadIdx.x; i < n; i += 256) {
    m0 = max(m0, a[i]);
    m1 = max(m1, b[i]);
  }
  s0[threadIdx.x] = m0;
  s1[threadIdx.x] = m1;
  __syncthreads();
  for (int st = 128; st > 0; st >>= 1) {
    if (threadIdx.x < st) {
      s0[threadIdx.x] = max(s0[threadIdx.x], s0[threadIdx.x + st]);
      s1[threadIdx.x] = max(s1[threadIdx.x], s1[threadIdx.x + st]);
    }
    __syncthreads();
  }
  if (threadIdx.x == 0) {
    caps[0] = s0[0] + 1;
    caps[1] = s1[0] + 1;
  }
}

// ---------------------------------------------------------------------------
// embed: h = feats @ in_w + in_b + pos_embed(coords)   (fp32 residual stream)
// ---------------------------------------------------------------------------
__global__ __launch_bounds__(256) void embed_kernel(const float* __restrict__ feats,
                                                    const int* __restrict__ coords,
                                                    const float* __restrict__ in_w,
                                                    const float* __restrict__ in_b,
                                                    float* __restrict__ h) {
  int id = blockIdx.x * 256 + threadIdx.x;
  if (id >= NVOX * CCH) return;
  int n = id / CCH, c = id - n * CCH;
  float acc = in_b[c];
#pragma unroll
  for (int k = 0; k < 8; ++k) acc += feats[n * 8 + k] * in_w[k * CCH + c];
  int axis = c / 256;
  int r = c - axis * 256;
  int f = r & 127;
  float freq = __expf(-(float)f * (9.210340371976184f / 128.0f));  // ln(10000)
  float phase = (float)coords[n * 3 + axis] * freq;
  acc += (r < 128) ? __sinf(phase) : __cosf(phase);
  h[id] = acc;
}

// ---------------------------------------------------------------------------
// layernorm (no affine) -> bf16 output (A-operand of following GEMM)
// ---------------------------------------------------------------------------
__global__ __launch_bounds__(256) void ln_kernel(const float* __restrict__ x,
                                                 unsigned short* __restrict__ y,
                                                 float eps) {
  int row = blockIdx.x;
  const float* xr = x + (size_t)row * CCH;
  float v[3];
  float s = 0.f, s2 = 0.f;
#pragma unroll
  for (int j = 0; j < 3; ++j) {
    v[j] = xr[threadIdx.x + j * 256];
    s += v[j];
    s2 += v[j] * v[j];
  }
#pragma unroll
  for (int off = 32; off >= 1; off >>= 1) {
    s += __shfl_xor(s, off, 64);
    s2 += __shfl_xor(s2, off, 64);
  }
  __shared__ float ss[4], ss2[4];
  int wave = threadIdx.x >> 6, lane = threadIdx.x & 63;
  if (lane == 0) { ss[wave] = s; ss2[wave] = s2; }
  __syncthreads();
  s = ss[0] + ss[1] + ss[2] + ss[3];
  s2 = ss2[0] + ss2[1] + ss2[2] + ss2[3];
  float mu = s * (1.0f / CCH);
  float var = s2 * (1.0f / CCH) - mu * mu;
  float rr = rsqrtf(var + eps);
  unsigned short* yr = y + (size_t)row * CCH;
#pragma unroll
  for (int j = 0; j < 3; ++j) yr[threadIdx.x + j * 256] = f2bf((v[j] - mu) * rr);
}

// ---------------------------------------------------------------------------
// weight convert: W fp32 [K][Nsrc] -> Wt bf16 [N][K] (transposed; n>=Nsrc -> 0)
// ---------------------------------------------------------------------------
__device__ __forceinline__ void wconv_tile(const float* __restrict__ W,
                                           unsigned short* __restrict__ Wt,
                                           int K, int Nsrc, int nt, int kt,
                                           float (*t)[65]) {
  int n0 = nt * 64, k0 = kt * 64;
  for (int e = threadIdx.x; e < 4096; e += 256) {
    int r = e >> 6, c = e & 63;
    int n = n0 + c;
    t[r][c] = (n < Nsrc) ? W[(size_t)(k0 + r) * Nsrc + n] : 0.f;
  }
  __syncthreads();
  for (int e = threadIdx.x; e < 4096; e += 256) {
    int rn = e >> 6, ck = e & 63;
    Wt[(size_t)(n0 + rn) * K + k0 + ck] = f2bf(t[ck][rn]);
  }
}

__global__ __launch_bounds__(256) void wconvert(const float* __restrict__ W,
                                                unsigned short* __restrict__ Wt,
                                                int K, int Nsrc) {
  __shared__ float t[64][65];
  wconv_tile(W, Wt, K, Nsrc, blockIdx.x, blockIdx.y, t);
}

// fused: all 4 weights of one block in one launch (1728 tiles)
__global__ __launch_bounds__(256) void wconvert4(const float* __restrict__ W0,
                                                 const float* __restrict__ W1,
                                                 const float* __restrict__ W2,
                                                 const float* __restrict__ W3,
                                                 unsigned short* __restrict__ D0,
                                                 unsigned short* __restrict__ D1,
                                                 unsigned short* __restrict__ D2,
                                                 unsigned short* __restrict__ D3) {
  __shared__ float t[64][65];
  int b = blockIdx.x;
  if (b < 432) {
    wconv_tile(W0, D0, 768, 2304, b / 12, b % 12, t);        // qkv 768x2304
  } else if (b < 576) {
    b -= 432;
    wconv_tile(W1, D1, 768, 768, b / 12, b % 12, t);         // proj 768x768
  } else if (b < 1152) {
    b -= 576;
    wconv_tile(W2, D2, 768, 3072, b / 12, b % 12, t);        // mlp1 768x3072
  } else {
    b -= 1152;
    wconv_tile(W3, D3, 3072, 768, b / 48, b % 48, t);        // mlp2 3072x768
  }
}

// ---------------------------------------------------------------------------
// bf16 MFMA GEMM, PIPE-deep counted-vmcnt pipeline (dynamic loop, r3-best):
//   per step: vmcnt((PIPE-1)*LPT) -> barrier -> ds_read frags -> lgkmcnt(0)
//   -> barrier -> prefetch tile t+PIPE into this buffer -> MFMA.
//   TM=128: 128x128 tile, wave = 64x64 quadrant (grid-rich dispatches).
//   TM=64 : 64x128 tile, wave = 64x32 strip  (grid-starved dispatches).
//   Endpgm hardening: vmcnt(0) drain before epilogue.
// gelu: branchless Abramowitz-Stegun 7.1.26 erf (|eps|<=1.5e-7) — the libm
//   erff epilogue was ~comparable VALU cost to the whole K-loop (r7 PMC:
//   VALUBusy 45% vs MfmaUtil 19%).
// out[M,Nn] = act(A[M,K] @ Bt[Nn,K]^T + bias); XCD-bijective tile swizzle.
// ---------------------------------------------------------------------------
__device__ __forceinline__ float gelu_fast(float x) {
  float z = fabsf(x) * 0.70710678118654752f;
  float t = 1.0f / (1.0f + 0.3275911f * z);
  float poly = t * (0.254829592f +
               t * (-0.284496736f +
               t * (1.421413741f +
               t * (-1.453152027f + t * 1.061405429f))));
  float erfz = 1.0f - poly * __expf(-z * z);     // erf(|x|/sqrt2), |err|<=1.5e-7
  erfz = copysignf(erfz, x);
  return 0.5f * x * (1.0f + erfz);
}

template <int ACT, int RES, int OUTBF, int PIPE, int TM>
__global__ __launch_bounds__(256) void gemm_mfma(const unsigned short* __restrict__ A,
                                                 const unsigned short* __restrict__ Bt,
                                                 const float* __restrict__ bias, int Nbias,
                                                 float* __restrict__ outf,
                                                 unsigned short* __restrict__ outb,
                                                 int Nn, int K) {
  constexpr int ATILE = TM * 32;    // shorts per A K-tile
  constexpr int BTILE = 128 * 32;   // shorts per B K-tile
  constexpr int NJ = (TM == 128) ? 4 : 2;
  __shared__ __align__(16) unsigned short As[PIPE * ATILE];
  __shared__ __align__(16) unsigned short Bs[PIPE * BTILE];
  const int tid = threadIdx.x;
  const int lane = tid & 63, w = tid >> 6;

  // m204 bijective XCD swizzle on the (x,y) tile grid
  int bx = blockIdx.x, by = blockIdx.y;
  {
    const int gx = gridDim.x, gy = gridDim.y;
    const int nwg = gx * gy;
    const int id = by * gx + bx;
    const int q = nwg >> 3, r = nwg & 7;
    const int xc = id & 7, off = id >> 3;
    const int nid = (xc < r ? xc * (q + 1) : r * (q + 1) + (xc - r) * q) + off;
    bx = nid % gx;
    by = nid / gx;
  }
  const int row0 = by * TM, col0 = bx * 128;
  const int wm = (TM == 128) ? (w >> 1) * 64 : 0;
  const int wn = (TM == 128) ? (w & 1) * 64 : w * 32;
  const int fm = lane & 15, fq = lane >> 4;

  // staging: thread covers slot c0 (and c0+256 where the tile has 512 slots);
  // slot s = row (s>>2), chunk (s&3). (c0+256) keeps chunk, adds 64 rows.
  const int c0 = w * 64 + lane;
  const unsigned short* pA0 = A + (size_t)(row0 + (c0 >> 2)) * K + (c0 & 3) * 8;
  const unsigned short* pA1 = pA0 + (size_t)64 * K;  // TM=128 only
  const unsigned short* pB0 = Bt + (size_t)(col0 + (c0 >> 2)) * K + (c0 & 3) * 8;
  const unsigned short* pB1 = pB0 + (size_t)64 * K;
  const int oL0 = w * 512;         // shorts; slots 0..255
  const int oL1 = w * 512 + 2048;  // slots 256..511

  v4f acc[4][NJ];
#pragma unroll
  for (int i = 0; i < 4; ++i)
#pragma unroll
    for (int j = 0; j < NJ; ++j) acc[i][j] = (v4f){0.f, 0.f, 0.f, 0.f};

  // prologue: stage tiles 0..PIPE-1
#pragma unroll
  for (int t = 0; t < PIPE; ++t) {
    async16(pA0 + t * 32, As + t * ATILE + oL0);
    if (TM == 128) async16(pA1 + t * 32, As + t * ATILE + oL1);
    async16(pB0 + t * 32, Bs + t * BTILE + oL0);
    async16(pB1 + t * 32, Bs + t * BTILE + oL1);
  }

  const int NT = K >> 5;
  int buf = 0;
  int kpf = PIPE * 32;  // k-offset (shorts) of next prefetch
  for (int t = 0; t < NT; ++t) {
    unsigned short* Ab = As + buf * ATILE;
    unsigned short* Bb = Bs + buf * BTILE;
    // wait until tile t's loads complete for this wave (PIPE-1 tiles stay
    // in flight); barrier -> complete for every wave
    if constexpr (TM == 128) {
      asm volatile("s_waitcnt vmcnt(%0)" ::"i"((PIPE - 1) * 4) : "memory");
    } else {
      asm volatile("s_waitcnt vmcnt(%0)" ::"i"((PIPE - 1) * 3) : "memory");
    }
    __builtin_amdgcn_s_barrier();
    v8s af[4], bfv[NJ];
#pragma unroll
    for (int i = 0; i < 4; ++i)
      af[i] = *(const v8s*)(Ab + (wm + i * 16 + fm) * 32 + fq * 8);
#pragma unroll
    for (int j = 0; j < NJ; ++j)
      bfv[j] = *(const v8s*)(Bb + (wn + j * 16 + fm) * 32 + fq * 8);
    // my ds_reads done -> barrier -> all waves' reads done: buffer reusable
    asm volatile("s_waitcnt lgkmcnt(0)" ::: "memory");
    __builtin_amdgcn_s_barrier();
    {
      // tail (kpf >= K): redundant reload of the current tile keeps the
      // vmcnt accounting uniform; data identical so overwrite is benign
      const int kq = (kpf < K) ? kpf : (kpf - PIPE * 32);
      async16(pA0 + kq, Ab + oL0);
      if (TM == 128) async16(pA1 + kq, Ab + oL1);
      async16(pB0 + kq, Bb + oL0);
      async16(pB1 + kq, Bb + oL1);
    }
#pragma unroll
    for (int i = 0; i < 4; ++i)
#pragma unroll
      for (int j = 0; j < NJ; ++j)
        acc[i][j] = __builtin_amdgcn_mfma_f32_16x16x32_bf16(af[i], bfv[j], acc[i][j], 0, 0, 0);
    kpf += 32;
    buf = (buf == PIPE - 1) ? 0 : buf + 1;
  }

  // drain all outstanding LDS-DMA before any wave can reach s_endpgm:
  // in-flight global_load_lds writes into deallocated LDS corrupt other blocks
  asm volatile("s_waitcnt vmcnt(0)" ::: "memory");
  __builtin_amdgcn_s_barrier();

#pragma unroll
  for (int i = 0; i < 4; ++i) {
    int row = row0 + wm + i * 16 + fq * 4;
#pragma unroll
    for (int j = 0; j < NJ; ++j) {
      int col = col0 + wn + j * 16 + fm;
      float b = (col < Nbias) ? bias[col] : 0.f;
#pragma unroll
      for (int r = 0; r < 4; ++r) {
        float v = acc[i][j][r] + b;
        if (ACT == 1) v = gelu_fast(v);
        size_t o = (size_t)(row + r) * Nn + col;
        if (RES) {
          outf[o] += v;
        } else if (OUTBF) {
          outb[o] = f2bf(v);
        } else {
          outf[o] = v;
        }
      }
    }
  }
}

// ---------------------------------------------------------------------------
// MFMA windowed attention: one wave per (window, head).
// Q,K fragments gathered DIRECTLY to registers (no LDS staging, no barrier);
// V staged row-major (6 coalesced v8s iters) then transposed in LDS.
// S = Q.K^T (3x3), in-register masked softmax (rden folded), P.V -> O.
// LDS: P(48x72) + Vt(64x72) + vox = 16.4 KB -> 9 blocks/CU.
// ---------------------------------------------------------------------------
__global__ __launch_bounds__(64) void attn_kernel(const unsigned short* __restrict__ qkv,
                                                  const int* __restrict__ idx,
                                                  const int* __restrict__ capPtr,
                                                  int total,
                                                  unsigned short* __restrict__ attn_out) {
  __shared__ __align__(16) unsigned short Pb[CAP * APITCH];  // V-rows, then P
  __shared__ __align__(16) unsigned short Vt[64 * APITCH];   // V transposed [d][j]
  __shared__ int vox_lds[64];
  const int cap = *capPtr;
  if (cap > CAP) return;  // loud failure rather than OOB
  const int nw = total / cap;
  const int tasks = nw * NH;
  const int lane = threadIdx.x;
  const int fm = lane & 15, fq = lane >> 4;
  const v8s z8 = {0, 0, 0, 0, 0, 0, 0, 0};

  for (int task = blockIdx.x; task < tasks; task += gridDim.x) {
    const int w = task / NH, hh = task - w * NH;
    int vox_i = NVOX;
    if (lane < cap) vox_i = idx[w * cap + lane];
    vox_lds[lane] = vox_i;
    __syncthreads();

    // stage V rows into Pb: 48 rows x 8 chunks of 8 bf16 (coalesced-ish v8s)
#pragma unroll
    for (int it = 0; it < 6; ++it) {
      int id = it * 64 + lane;  // 0..383
      int j = id >> 3, c = id & 7;
      int vj = vox_lds[j];
      v8s v8 = z8;
      if (vj < NVOX)
        v8 = *(const v8s*)(qkv + (size_t)vj * (3 * CCH) + 2 * CCH + hh * DH + c * 8);
      *(v8s*)(Pb + j * APITCH + c * 8) = v8;
    }

    // gather Q,K fragments directly to registers (rows mi*16+fm, k = ks*32+fq*8)
    v8s qf[3][2], kf[3][2];
#pragma unroll
    for (int mi = 0; mi < 3; ++mi) {
      int row = mi * 16 + fm;
      int vj = (row < cap) ? vox_lds[row] : NVOX;
      const unsigned short* base = qkv + (size_t)vj * (3 * CCH) + hh * DH + fq * 8;
#pragma unroll
      for (int ks = 0; ks < 2; ++ks) {
        qf[mi][ks] = (vj < NVOX) ? *(const v8s*)(base + ks * 32) : z8;
        kf[mi][ks] = (vj < NVOX) ? *(const v8s*)(base + CCH + ks * 32) : z8;
      }
    }

    // S = Q . K^T  (register-only)
    v4f s_acc[3][3];
#pragma unroll
    for (int mi = 0; mi < 3; ++mi)
#pragma unroll
      for (int jt = 0; jt < 3; ++jt) s_acc[mi][jt] = (v4f){0.f, 0.f, 0.f, 0.f};
#pragma unroll
    for (int ks = 0; ks < 2; ++ks)
#pragma unroll
      for (int mi = 0; mi < 3; ++mi)
#pragma unroll
        for (int jt = 0; jt < 3; ++jt)
          s_acc[mi][jt] = __builtin_amdgcn_mfma_f32_16x16x32_bf16(qf[mi][ks], kf[jt][ks], s_acc[mi][jt], 0, 0, 0);

    __syncthreads();  // V rows staged
    // transpose Pb (rows j, cols d) -> Vt (rows d, cols j); lane = column j
    if (lane < CAP) {
#pragma unroll
      for (int c = 0; c < 8; ++c) {
        v8s r8 = *(const v8s*)(Pb + lane * APITCH + c * 8);
#pragma unroll
        for (int e = 0; e < 8; ++e) Vt[(c * 8 + e) * APITCH + lane] = r8[e];
      }
    } else {
#pragma unroll
      for (int d = 0; d < 64; ++d) Vt[d * APITCH + lane] = 0;  // j-padding
    }
    __syncthreads();  // transpose reads of Pb done; P may overwrite

    // masked softmax in C-layout registers; scale 1/8 folded into exp,
    // 1/den folded into P. Scores are O(1) here -> exp without max-subtract.
    bool va0 = (fm < cap) && (vox_lds[fm] < NVOX);
    bool va1 = (16 + fm < cap) && (vox_lds[16 + fm] < NVOX);
    bool va2 = (32 + fm < cap) && (vox_lds[32 + fm] < NVOX);
#pragma unroll
    for (int mi = 0; mi < 3; ++mi) {
#pragma unroll
      for (int r = 0; r < 4; ++r) {
        float e0 = va0 ? __expf(s_acc[mi][0][r] * 0.125f) : 0.f;
        float e1 = va1 ? __expf(s_acc[mi][1][r] * 0.125f) : 0.f;
        float e2 = va2 ? __expf(s_acc[mi][2][r] * 0.125f) : 0.f;
        float den = e0 + e1 + e2;
        den += __shfl_xor(den, 1, 64);
        den += __shfl_xor(den, 2, 64);
        den += __shfl_xor(den, 4, 64);
        den += __shfl_xor(den, 8, 64);
        float rden = (den > 0.f) ? 1.0f / den : 0.f;
        int row = mi * 16 + fq * 4 + r;
        Pb[row * APITCH + fm] = f2bf(e0 * rden);
        Pb[row * APITCH + 16 + fm] = f2bf(e1 * rden);
        Pb[row * APITCH + 32 + fm] = f2bf(e2 * rden);
      }
    }
    if (lane < CAP) {  // zero P cols 48..64 (k padding for PV)
      *(v8s*)(Pb + lane * APITCH + 48) = z8;
      *(v8s*)(Pb + lane * APITCH + 56) = z8;
    }
    __syncthreads();

    // O = P . V   (rows i, cols d)
    v4f o_acc[3][4];
#pragma unroll
    for (int mi = 0; mi < 3; ++mi)
#pragma unroll
      for (int nt = 0; nt < 4; ++nt) o_acc[mi][nt] = (v4f){0.f, 0.f, 0.f, 0.f};
#pragma unroll
    for (int ks = 0; ks < 2; ++ks) {
      v8s pf[3], vf[4];
#pragma unroll
      for (int mi = 0; mi < 3; ++mi)
        pf[mi] = *(const v8s*)(Pb + (mi * 16 + fm) * APITCH + ks * 32 + fq * 8);
#pragma unroll
      for (int nt = 0; nt < 4; ++nt)
        vf[nt] = *(const v8s*)(Vt + (nt * 16 + fm) * APITCH + ks * 32 + fq * 8);
#pragma unroll
      for (int mi = 0; mi < 3; ++mi)
#pragma unroll
        for (int nt = 0; nt < 4; ++nt)
          o_acc[mi][nt] = __builtin_amdgcn_mfma_f32_16x16x32_bf16(pf[mi], vf[nt], o_acc[mi][nt], 0, 0, 0);
    }

    // scatter store O rows
#pragma unroll
    for (int mi = 0; mi < 3; ++mi) {
#pragma unroll
      for (int r = 0; r < 4; ++r) {
        int i = mi * 16 + fq * 4 + r;
        int vox = vox_lds[i];
        if (i < cap && vox < NVOX) {
          unsigned short* ob = attn_out + (size_t)vox * CCH + hh * DH + fm;
#pragma unroll
          for (int nt = 0; nt < 4; ++nt) ob[nt * 16] = f2bf(o_acc[mi][nt][r]);
        }
      }
    }
    __syncthreads();  // Pb/Vt reads done before next task's staging
  }
}

// ---------------------------------------------------------------------------
// gaussian decode: reads padded [N][512] fp32, writes d_out [N][448]
// ---------------------------------------------------------------------------
__global__ __launch_bounds__(256) void decode_kernel(const float* __restrict__ outpad,
                                                     const int* __restrict__ coords,
                                                     const float* __restrict__ perturb,
                                                     float* __restrict__ out) {
  __shared__ float row[OUT_CH];
  const int n = blockIdx.x;
  const float* src = outpad + (size_t)n * OUT_PAD;
  for (int e = threadIdx.x; e < OUT_CH; e += 256) row[e] = src[e];
  __syncthreads();
  float* o = out + (size_t)n * OUT_CH;
  for (int e = threadIdx.x; e < OUT_CH; e += 256) {
    int g = e / 14, j = e - g * 14;
    float v;
    if (j < 3) {
      float xyz = ((float)coords[n * 3 + j] + 0.5f) * (1.0f / 64.0f);
      v = xyz + tanhf(row[g * 3 + j] + perturb[g * 3 + j]) * (0.75f / 64.0f);
    } else if (j < 6) {
      v = row[96 + g * 3 + (j - 3)];
    } else if (j < 9) {
      v = row[192 + g * 3 + (j - 6)];
    } else if (j < 13) {
      v = row[288 + g * 4 + (j - 9)] * 0.1f;
    } else {
      v = row[416 + g];
    }
    o[e] = v;
  }
}

// ---------------------------------------------------------------------------
extern "C" void kernel_launch(void* const* d_in, const int* in_sizes, int n_in,
                              void* d_out, int out_size, void* d_ws, size_t ws_size,
                              hipStream_t stream) {
  const float* feats = (const float*)d_in[0];
  const int* coords = (const int*)d_in[1];
  const float* in_w = (const float*)d_in[2];
  const float* in_b = (const float*)d_in[3];
  const float* qkv_w = (const float*)d_in[4];
  const float* qkv_b = (const float*)d_in[5];
  const float* proj_w = (const float*)d_in[6];
  const float* proj_b = (const float*)d_in[7];
  const float* mlp_w1 = (const float*)d_in[8];
  const float* mlp_b1 = (const float*)d_in[9];
  const float* mlp_w2 = (const float*)d_in[10];
  const float* mlp_b2 = (const float*)d_in[11];
  const float* out_w = (const float*)d_in[12];
  const float* out_b = (const float*)d_in[13];
  const float* perturb = (const float*)d_in[14];
  const int* idx0 = (const int*)d_in[15];
  const int* vslot0 = (const int*)d_in[18];
  const int* idx1 = (const int*)d_in[19];
  const int* vslot1 = (const int*)d_in[22];
  const int total0 = in_sizes[15];
  const int total1 = in_sizes[19];

  char* p = (char*)d_ws;
  int* caps = (int*)p;                                                    // 256 B
  float* h = (float*)(p + 256);                                           // 25165824
  unsigned short* abuf = (unsigned short*)(p + 256 + 25165824);           // 12582912
  unsigned short* big = (unsigned short*)(p + 256 + 37748736);            // 50331648
  unsigned short* wst = (unsigned short*)(p + 256 + 88080384);            // 14155776
  float* outpad = (float*)(p + 256 + 102236160);                          // 16777216
  const size_t OQ = 0;
  const size_t OP = (size_t)768 * 2304;
  const size_t OM1 = OP + (size_t)768 * 768;
  const size_t OM2 = OM1 + (size_t)768 * 3072;

  cap_kernel<<<1, 256, 0, stream>>>(vslot0, vslot1, NVOX, caps);
  embed_kernel<<<(NVOX * CCH + 255) / 256, 256, 0, stream>>>(feats, coords, in_w, in_b, h);

  for (int i = 0; i < NBLK; ++i) {
    const int* idx = (i & 1) ? idx1 : idx0;
    const int* capP = (i & 1) ? caps + 1 : caps;
    const int total = (i & 1) ? total1 : total0;

    wconvert4<<<1728, 256, 0, stream>>>(
        qkv_w + (size_t)i * 768 * 2304, proj_w + (size_t)i * 768 * 768,
        mlp_w1 + (size_t)i * 768 * 3072, mlp_w2 + (size_t)i * 3072 * 768,
        wst + OQ, wst + OP, wst + OM1, wst + OM2);

    ln_kernel<<<NVOX, 256, 0, stream>>>(h, abuf, 1e-6f);
    gemm_mfma<0, 0, 1, 3, 128><<<dim3(18, 64), 256, 0, stream>>>(
        abuf, wst + OQ, qkv_b + (size_t)i * 2304, 2304, nullptr, big, 2304, 768);
    attn_kernel<<<4096, 64, 0, stream>>>(big, idx, capP, total, abuf);
    gemm_mfma<0, 1, 0, 3, 64><<<dim3(6, 128), 256, 0, stream>>>(
        abuf, wst + OP, proj_b + (size_t)i * 768, 768, h, nullptr, 768, 768);
    ln_kernel<<<NVOX, 256, 0, stream>>>(h, abuf, 1e-6f);
    gemm_mfma<1, 0, 1, 3, 128><<<dim3(24, 64), 256, 0, stream>>>(
        abuf, wst + OM1, mlp_b1 + (size_t)i * 3072, 3072, nullptr, big, 3072, 768);
    gemm_mfma<0, 1, 0, 3, 64><<<dim3(6, 128), 256, 0, stream>>>(
        big, wst + OM2, mlp_b2 + (size_t)i * 768, 768, h, nullptr, 768, 3072);
  }

  ln_kernel<<<NVOX, 256, 0, stream>>>(h, abuf, 1e-5f);
  wconvert<<<dim3(8, 12), 256, 0, stream>>>(out_w, wst + OQ, 768, OUT_CH);
  gemm_mfma<0, 0, 0, 3, 64><<<dim3(4, 128), 256, 0, stream>>>(
      abuf, wst + OQ, out_b, OUT_CH, outpad, nullptr, OUT_PAD, 768);
  decode_kernel<<<NVOX, 256, 0, stream>>>(outpad, coords, perturb, (float*)d_out);
}